// Round 1
// 1881.410 us; speedup vs baseline: 1.3327x; 1.3327x over previous
//
#include <hip/hip_runtime.h>
#include <hip/hip_bf16.h>

using bf = __hip_bfloat16;
typedef unsigned short u16;

// Model dims
#define V_   32000
#define DM   1024
#define LQ   1024
#define BB   4
#define NLAY 2
#define NE   8
#define HH   1024
#define DS   16
#define DC   4
#define DI   2048
#define DTR  64
#define NTOK (BB*LQ)   // 4096

// scan chunking
#define NC 8
#define CL (LQ/NC)     // 128

typedef __attribute__((ext_vector_type(8))) short s8v;
typedef __attribute__((ext_vector_type(4))) float f4v;

__device__ inline float tofl(float x) { return x; }
__device__ inline float tofl(bf x) { return __bfloat162float(x); }

template<typename T> __device__ inline T fromf(float v);
template<> __device__ inline float fromf<float>(float v) { return v; }
template<> __device__ inline bf fromf<bf>(float v) { return __float2bfloat16(v); }

__device__ inline u16 f2bfu(float x) {
    bf h = __float2bfloat16(x);
    return __builtin_bit_cast(u16, h);
}
__device__ inline float bfu2f(u16 u) {
    bf h = __builtin_bit_cast(bf, u);
    return __bfloat162float(h);
}

__device__ inline f4v mfma16(s8v a, s8v b, f4v c) {
    return __builtin_amdgcn_mfma_f32_16x16x32_bf16(a, b, c, 0, 0, 0);
}

// async global->LDS, 16B per lane. LDS dest is wave-uniform base + lane*16;
// global src is per-lane.
__device__ __forceinline__ void gl2lds16(const u16* g, u16* l) {
    __builtin_amdgcn_global_load_lds(
        (const __attribute__((address_space(1))) unsigned int*)g,
        (__attribute__((address_space(3))) unsigned int*)l, 16, 0, 0);
}

// ---------------------------------------------------------------------------
// split2: f32 [R,K] (row stride ldin) -> bf16 [R,2K]; per 32-col block b:
// out[r][b*64 + j]   = bf16(x)          (hi)
// out[r][b*64+32+ j] = bf16(x - hi)     (lo)
// grid = R*K/1024, 256 threads, 4 elems/thread.
// ---------------------------------------------------------------------------
__global__ __launch_bounds__(256) void split2_kernel(
    const float* __restrict__ in, int ldin,
    u16* __restrict__ out, int K)
{
    int id = blockIdx.x * 256 + threadIdx.x;
    int e4 = id * 4;
    int r = e4 / K;
    int k = e4 - r * K;
    float4 v = *(const float4*)(in + (size_t)r * ldin + k);
    int b = k >> 5, j = k & 31;
    ushort4 hi, lo;
    hi.x = f2bfu(v.x); lo.x = f2bfu(v.x - bfu2f(hi.x));
    hi.y = f2bfu(v.y); lo.y = f2bfu(v.y - bfu2f(hi.y));
    hi.z = f2bfu(v.z); lo.z = f2bfu(v.z - bfu2f(hi.z));
    hi.w = f2bfu(v.w); lo.w = f2bfu(v.w - bfu2f(hi.w));
    u16* o = out + (size_t)r * (2 * K) + b * 64 + j;
    *(ushort4*)o = hi;
    *(ushort4*)(o + 32) = lo;
}

__global__ __launch_bounds__(256) void zerof4_kernel(float4* __restrict__ p) {
    p[(size_t)blockIdx.x * 256 + threadIdx.x] = make_float4(0.f, 0.f, 0.f, 0.f);
}

// ---------------------------------------------------------------------------
// MFMA GEMM on pre-split bf16 operands.
// TERMS=3: A is split2 [M,2K], B is split2 [N,2K]; acc gets Ah*Bh + Ah*Bl + Al*Bh
//          (identical per-element accumulation order to the old fused kernel).
// TERMS=2: A is plain bf16 [M,K], B split2; acc gets A*Bh + A*Bl.
// Tile 128 x BN (BN in {128,64}), BK=32, 4 waves, LDS filled via
// global_load_lds dwordx4 (linear layout), ds_read_b128 fragments.
// Expert mode (cnt!=null): z = expert, optional row gather/scatter via perm.
// Split-K mode (cnt==null && nqz>0): z = K-chunk, atomicAdd f32 epilogue.
// ---------------------------------------------------------------------------
template<typename TC, int TERMS, int BN>
__global__ __launch_bounds__(256, 3) void gemm_s(
    const u16* __restrict__ A, int lda,
    const u16* __restrict__ Bw, int ldb,
    TC* __restrict__ C, int ldc,
    int M, int N, int K32,
    const float* __restrict__ bias, int epi,        // 0 none, 1 softplus, 2 relu
    const int* __restrict__ cnt, const int* __restrict__ offs,
    const int* __restrict__ perm, int permmode,
    const float* __restrict__ scale,
    long long strideB_e, long long stride_bias_e,
    int nqz, int atomic_out)
{
    int zb = blockIdx.z;
    int Meff = M, rowoff = 0;
    int q0 = 0, q1 = K32;
    if (cnt) {
        Meff = cnt[zb];
        rowoff = offs[zb];
        Bw += (size_t)zb * strideB_e;
        if (bias) bias += (size_t)zb * stride_bias_e;
    } else if (nqz) {
        q0 = zb * nqz; q1 = q0 + nqz;
    }
    int m0 = blockIdx.y * 128;
    if (m0 >= Meff) return;
    int n0 = blockIdx.x * BN;

    constexpr int MI  = (BN == 128) ? 4 : 2;
    constexpr int NBR = BN / 64;                 // B staging rounds

    __shared__ u16 AsH[128 * 32];
    __shared__ u16 AsL[(TERMS == 3) ? 128 * 32 : 8];
    __shared__ u16 BsH[BN * 32];
    __shared__ u16 BsL[BN * 32];

    int t = threadIdx.x, lane = t & 63, wv = t >> 6;
    int wm = (BN == 128) ? (wv & 1) * 64 : wv * 32;
    int wn = (BN == 128) ? (wv >> 1) * 64 : 0;
    int fr = lane & 15, kq = lane >> 4;
    int chunk = lane & 3;

    // per-lane staged rows (wave wv, round r covers rows r*64+wv*16 .. +15)
    int arow[2], brow[2];
#pragma unroll
    for (int r = 0; r < 2; r++) {
        int m = m0 + r * 64 + wv * 16 + (lane >> 2);
        int ar = rowoff + ((m < Meff) ? m : 0);   // clamp to a valid row; never stored
        arow[r] = (permmode & 1) ? perm[ar] : ar;
    }
#pragma unroll
    for (int r = 0; r < NBR; r++) {
        int n = n0 + r * 64 + wv * 16 + (lane >> 2);
        brow[r] = (n < N) ? n : 0;                // clamped rows feed unused columns
    }

    f4v acc[MI][4];
#pragma unroll
    for (int i = 0; i < MI; i++)
#pragma unroll
        for (int j = 0; j < 4; j++) acc[i][j] = 0.f;

    for (int q = q0; q < q1; ++q) {
        size_t acol = (TERMS == 3) ? ((size_t)q * 64 + chunk * 8)
                                   : ((size_t)q * 32 + chunk * 8);
        size_t bcol = (size_t)q * 64 + chunk * 8;
#pragma unroll
        for (int r = 0; r < 2; r++) {
            const u16* ap = A + (size_t)arow[r] * lda + acol;
            gl2lds16(ap, &AsH[(r * 64 + wv * 16) * 32]);
            if constexpr (TERMS == 3)
                gl2lds16(ap + 32, &AsL[(r * 64 + wv * 16) * 32]);
        }
#pragma unroll
        for (int r = 0; r < NBR; r++) {
            const u16* bp = Bw + (size_t)brow[r] * ldb + bcol;
            gl2lds16(bp, &BsH[(r * 64 + wv * 16) * 32]);
            gl2lds16(bp + 32, &BsL[(r * 64 + wv * 16) * 32]);
        }
        __syncthreads();   // compiler drains vmcnt(0) before s_barrier

        s8v ahf[MI], bhf[4], blf[4];
#pragma unroll
        for (int mi = 0; mi < MI; mi++)
            ahf[mi] = *(const s8v*)&AsH[(wm + mi * 16 + fr) * 32 + kq * 8];
#pragma unroll
        for (int ni = 0; ni < 4; ni++)
            bhf[ni] = *(const s8v*)&BsH[(wn + ni * 16 + fr) * 32 + kq * 8];
#pragma unroll
        for (int ni = 0; ni < 4; ni++)
            blf[ni] = *(const s8v*)&BsL[(wn + ni * 16 + fr) * 32 + kq * 8];
#pragma unroll
        for (int mi = 0; mi < MI; mi++)
#pragma unroll
            for (int ni = 0; ni < 4; ni++) {
                acc[mi][ni] = mfma16(ahf[mi], bhf[ni], acc[mi][ni]);   // hi*hi
                acc[mi][ni] = mfma16(ahf[mi], blf[ni], acc[mi][ni]);   // hi*lo
            }
        if constexpr (TERMS == 3) {
            s8v alf[MI];
#pragma unroll
            for (int mi = 0; mi < MI; mi++)
                alf[mi] = *(const s8v*)&AsL[(wm + mi * 16 + fr) * 32 + kq * 8];
#pragma unroll
            for (int mi = 0; mi < MI; mi++)
#pragma unroll
                for (int ni = 0; ni < 4; ni++)
                    acc[mi][ni] = mfma16(alf[mi], bhf[ni], acc[mi][ni]);  // lo*hi
        }
        __syncthreads();
    }

    // epilogue: C row = (lane>>4)*4 + reg, col = lane&15
#pragma unroll
    for (int mi = 0; mi < MI; mi++) {
#pragma unroll
        for (int r4 = 0; r4 < 4; r4++) {
            int m = m0 + wm + mi * 16 + kq * 4 + r4;
            if (m >= Meff) continue;
            long long crow;
            float sc = 1.f;
            int ar = rowoff + m;
            if (permmode & 2) { int tok = perm[ar]; crow = tok; sc = scale[tok]; }
            else crow = ar;
#pragma unroll
            for (int ni = 0; ni < 4; ni++) {
                int n = n0 + wn + ni * 16 + fr;
                if (n >= N) continue;
                float v = acc[mi][ni][r4];
                if (bias) v += bias[n];
                if (epi == 1) v = (v > 20.f) ? v : log1pf(__expf(v));
                else if (epi == 2) v = fmaxf(v, 0.f);
                v *= sc;
                long long idx = crow * ldc + n;
                if constexpr (sizeof(TC) == 4) {
                    if (atomic_out) atomicAdd((float*)C + idx, v);
                    else C[idx] = fromf<TC>(v);
                } else {
                    C[idx] = fromf<TC>(v);
                }
            }
        }
    }
}

// ---------------------------------------------------------------------------
__global__ __launch_bounds__(256) void embed_kernel(
    const int* __restrict__ tokens, const float* __restrict__ emb,
    const float* __restrict__ pos, float* __restrict__ X)
{
    int id = blockIdx.x * 256 + threadIdx.x;   // NTOK*DM threads
    int r = id >> 10, d = id & 1023;
    int l = r & (LQ - 1);
    int tok = tokens[r];
    X[id] = emb[(size_t)tok * DM + d] + pos[l * DM + d];
}

// causal depthwise conv (DC=4) + SiLU.  u lives in XZ[:, 0:DI], row stride 2*DI
__global__ __launch_bounds__(256) void conv_kernel(
    const bf* __restrict__ XZ, const float* __restrict__ cw,
    const float* __restrict__ cb, bf* __restrict__ UC)
{
    int id = blockIdx.x * 256 + threadIdx.x;   // NTOK*DI threads
    int d = id & (DI - 1);
    int r = id >> 11;
    int l = r & (LQ - 1);
    float acc = cb[d];
#pragma unroll
    for (int j = 0; j < DC; j++) {
        int ll = l - (DC - 1) + j;
        if (ll >= 0)
            acc += tofl(XZ[(size_t)(r - (DC - 1) + j) * (2 * DI) + d]) * cw[d * DC + j];
    }
    float sg = 1.f / (1.f + __expf(-acc));
    UC[id] = __float2bfloat16(acc * sg);
}

// ---------------------------------------------------------------------------
// Chunked parallel scan. PHASE 0: scan chunks from h=0, emit chunk-final h +
// sum(dt). combine: compose chunk-initial states. PHASE 1: rescan from Hin,
// fuse +u*D and *silu(z), write y (f32) over DT in place.
// ---------------------------------------------------------------------------
template<int PHASE>
__global__ __launch_bounds__(256) void scan_chunk(
    const bf* __restrict__ UC, float* __restrict__ DT,
    const float* __restrict__ W96, const bf* __restrict__ XZ,
    const float* __restrict__ A_log, const float* __restrict__ D_ssm,
    float* __restrict__ Hout, float* __restrict__ Stot,
    const float* __restrict__ Hin)
{
    int d = blockIdx.x * 256 + threadIdx.x;    // DI/256 blocks in x
    int c = blockIdx.y, b = blockIdx.z;
    float A[DS];
#pragma unroll
    for (int n = 0; n < DS; n++) A[n] = -__expf(A_log[d * DS + n]);
    float Dv = D_ssm[d];
    float h[DS];
    size_t hbase = ((size_t)(b * DI + d) * NC + c) * DS;
    if (PHASE == 0) {
#pragma unroll
        for (int n = 0; n < DS; n++) h[n] = 0.f;
    } else {
#pragma unroll
        for (int n = 0; n < DS; n += 4)
            *(float4*)&h[n] = *(const float4*)&Hin[hbase + n];
    }
    float S = 0.f;

    for (int t = 0; t < CL; t++) {
        int r = (b << 10) + c * CL + t;
        float u = tofl(UC[(size_t)r * DI + d]);
        float dt = DT[(size_t)r * DI + d];
        float du = dt * u;
        if (PHASE == 0) S += dt;
        float y = 0.f;
#pragma unroll
        for (int n = 0; n < DS; n++) {
            float Bv = W96[r * 96 + DTR + n];
            h[n] = __expf(dt * A[n]) * h[n] + du * Bv;
            if (PHASE == 1) y += h[n] * W96[r * 96 + DTR + DS + n];
        }
        if (PHASE == 1) {
            float z = tofl(XZ[(size_t)r * (2 * DI) + DI + d]);
            float sil = z / (1.f + __expf(-z));
            DT[(size_t)r * DI + d] = (y + u * Dv) * sil;
        }
    }
    if (PHASE == 0) {
#pragma unroll
        for (int n = 0; n < DS; n += 4)
            *(float4*)&Hout[hbase + n] = *(const float4*)&h[n];
        Stot[(size_t)(b * DI + d) * NC + c] = S;
    }
}

__global__ __launch_bounds__(256) void scan_combine(
    const float* __restrict__ Hout, const float* __restrict__ Stot,
    const float* __restrict__ A_log, float* __restrict__ Hin)
{
    int id = blockIdx.x * 256 + threadIdx.x;   // BB*DI*DS = 131072 threads
    int n = id & (DS - 1);
    int d = (id >> 4) & (DI - 1);
    int b = id >> 15;
    float A = -__expf(A_log[d * DS + n]);
    float h = 0.f;
    size_t base = (size_t)(b * DI + d) * NC * DS + n;
    size_t sbase = (size_t)(b * DI + d) * NC;
    for (int c = 0; c < NC; c++) {
        Hin[base + (size_t)c * DS] = h;
        h = __expf(A * Stot[sbase + c]) * h + Hout[base + (size_t)c * DS];
    }
}

// ---------------------------------------------------------------------------
// LN(src) * g + b added into f32 residual stream X.  One block per row.
__global__ __launch_bounds__(256) void ln_residual_kernel(
    float* __restrict__ X, const float* __restrict__ src,
    const float* __restrict__ g, const float* __restrict__ b)
{
    int row = blockIdx.x, tid = threadIdx.x;
    __shared__ float red[256];
    float v[4];
    float s = 0.f;
#pragma unroll
    for (int i = 0; i < 4; i++) { v[i] = src[(size_t)row * DM + tid + 256 * i]; s += v[i]; }
    red[tid] = s; __syncthreads();
    for (int o = 128; o > 0; o >>= 1) { if (tid < o) red[tid] += red[tid + o]; __syncthreads(); }
    float mean = red[0] * (1.f / DM);
    __syncthreads();
    float vs = 0.f;
#pragma unroll
    for (int i = 0; i < 4; i++) { float dd = v[i] - mean; vs += dd * dd; }
    red[tid] = vs; __syncthreads();
    for (int o = 128; o > 0; o >>= 1) { if (tid < o) red[tid] += red[tid + o]; __syncthreads(); }
    float rstd = rsqrtf(red[0] * (1.f / DM) + 1e-5f);
#pragma unroll
    for (int i = 0; i < 4; i++) {
        int c = tid + 256 * i;
        X[(size_t)row * DM + c] += (v[i] - mean) * rstd * g[c] + b[c];
    }
}

// gate: logits -> softmax max/argmax -> top_idx/top_w + per-expert counts
__global__ __launch_bounds__(64) void gate_kernel(
    const float* __restrict__ X, const float* __restrict__ gw, const float* __restrict__ gb,
    int* __restrict__ top_idx, float* __restrict__ top_w, int* __restrict__ cnt)
{
    int n = blockIdx.x;
    int lane = threadIdx.x;
    float acc[NE] = {};
    for (int k = lane; k < DM; k += 64) {
        float xv = X[(size_t)n * DM + k];
#pragma unroll
        for (int e = 0; e < NE; e++) acc[e] += xv * gw[e * DM + k];
    }
#pragma unroll
    for (int e = 0; e < NE; e++)
        for (int o = 32; o > 0; o >>= 1) acc[e] += __shfl_down(acc[e], o);
    if (lane == 0) {
        float logits[NE];
        float best = -1e30f; int bi = 0;
#pragma unroll
        for (int e = 0; e < NE; e++) {
            logits[e] = acc[e] + gb[e];
            if (logits[e] > best) { best = logits[e]; bi = e; }
        }
        float s = 0.f;
#pragma unroll
        for (int e = 0; e < NE; e++) s += __expf(logits[e] - best);
        top_idx[n] = bi;
        top_w[n] = 1.f / s;
        atomicAdd(&cnt[bi], 1);
    }
}

__global__ void zero8_kernel(int* p) { if (threadIdx.x < 8) p[threadIdx.x] = 0; }

__global__ void offsets_kernel(const int* __restrict__ cnt, int* __restrict__ offs, int* __restrict__ pos)
{
    if (threadIdx.x == 0) {
        int a = 0;
        for (int e = 0; e < NE; e++) { offs[e] = a; a += cnt[e]; pos[e] = 0; }
        offs[NE] = a;
    }
}

__global__ __launch_bounds__(256) void scatter_kernel(
    const int* __restrict__ top_idx, const int* __restrict__ offs,
    int* __restrict__ pos, int* __restrict__ perm)
{
    int n = blockIdx.x * 256 + threadIdx.x;
    if (n >= NTOK) return;
    int e = top_idx[n];
    int slot = atomicAdd(&pos[e], 1);
    perm[offs[e] + slot] = n;
}

__global__ __launch_bounds__(256) void rowmask_kernel(const float* __restrict__ X, float* __restrict__ maskf)
{
    int row = blockIdx.x, tid = threadIdx.x;
    __shared__ float red[256];
    float s = 0.f;
    for (int i = tid; i < DM; i += 256) s += X[(size_t)row * DM + i];
    red[tid] = s; __syncthreads();
    for (int o = 128; o > 0; o >>= 1) { if (tid < o) red[tid] += red[tid + o]; __syncthreads(); }
    if (tid == 0) maskf[row] = (red[0] != 0.f) ? 1.f : 0.f;
}

__global__ __launch_bounds__(256) void cntb_kernel(const float* __restrict__ maskf, float* __restrict__ cntb)
{
    int b = blockIdx.x, tid = threadIdx.x;
    __shared__ float red[256];
    float s = 0.f;
    for (int i = tid; i < LQ; i += 256) s += maskf[b * LQ + i];
    red[tid] = s; __syncthreads();
    for (int o = 128; o > 0; o >>= 1) { if (tid < o) red[tid] += red[tid + o]; __syncthreads(); }
    if (tid == 0) cntb[b] = red[0];
}

__global__ __launch_bounds__(256) void pooled_kernel(
    const float* __restrict__ X, const float* __restrict__ maskf,
    const float* __restrict__ cntb, float* __restrict__ pooled)
{
    int d = blockIdx.x * 256 + threadIdx.x;
    int b = blockIdx.y;
    float s = 0.f;
    for (int l = 0; l < LQ; l++)
        s += X[(size_t)((b << 10) + l) * DM + d] * maskf[(b << 10) + l];
    pooled[b * DM + d] = s / fmaxf(cntb[b], 1.f);
}

__global__ __launch_bounds__(128) void head_kernel(
    const float* __restrict__ pooled,
    const float* __restrict__ fc1w, const float* __restrict__ fc1b,
    const float* __restrict__ fc2w, const float* __restrict__ fc2b,
    float* __restrict__ out)
{
    int b = blockIdx.x;
    int j = threadIdx.x;   // 128
    __shared__ float hbuf[128];
    float acc = fc1b[j];
    for (int k = 0; k < DM; k++) acc += pooled[b * DM + k] * fc1w[j * DM + k];
    hbuf[j] = fmaxf(acc, 0.f);
    __syncthreads();
    if (j < 2) {
        float o = fc2b[j];
        for (int k = 0; k < 128; k++) o += hbuf[k] * fc2w[j * 128 + k];
        out[b * 2 + j] = o;
    }
}

// ---------------------------------------------------------------------------
extern "C" void kernel_launch(void* const* d_in, const int* in_sizes, int n_in,
                              void* d_out, int out_size, void* d_ws, size_t ws_size,
                              hipStream_t stream)
{
    const int*   tokens = (const int*)d_in[0];
    const float* emb    = (const float*)d_in[1];
    const float* pos    = (const float*)d_in[2];
    const float* in_w   = (const float*)d_in[3];
    const float* conv_w = (const float*)d_in[4];
    const float* conv_b = (const float*)d_in[5];
    const float* xp_w   = (const float*)d_in[6];
    const float* dt_w   = (const float*)d_in[7];
    const float* dt_b   = (const float*)d_in[8];
    const float* A_log  = (const float*)d_in[9];
    const float* D_ssm  = (const float*)d_in[10];
    const float* out_w  = (const float*)d_in[11];
    const float* ln1_g  = (const float*)d_in[12];
    const float* ln1_b  = (const float*)d_in[13];
    const float* ln2_g  = (const float*)d_in[14];
    const float* ln2_b  = (const float*)d_in[15];
    const float* gate_w = (const float*)d_in[16];
    const float* gate_b = (const float*)d_in[17];
    const float* e_w1   = (const float*)d_in[18];
    const float* e_b1   = (const float*)d_in[19];
    const float* e_w2   = (const float*)d_in[20];
    const float* e_b2   = (const float*)d_in[21];
    const float* fc1_w  = (const float*)d_in[22];
    const float* fc1_b  = (const float*)d_in[23];
    const float* fc2_w  = (const float*)d_in[24];
    const float* fc2_b  = (const float*)d_in[25];
    float* outp = (float*)d_out;

    // workspace layout (~111 MB peak, heavy overlay reuse):
    //  xzraw (33.5MB): XZ -> DTS -> H1(front)+H1S(back) -> MAM2(front)
    //  ucraw (16.8MB): XS -> UC -> MAM1 -> XS
    //  dtraw (33.5MB): weight-split buf -> DT -> weight-split buf (experts)
    //  Hout/Hin (4MB each): scan state; also W96S / dt_w-split scratch
    char* wsb = (char*)d_ws;
    size_t off = 0;
    auto alloc = [&](size_t bytes) { char* p = wsb + off; off += (bytes + 255) & ~(size_t)255; return p; };
    float* X    = (float*)alloc((size_t)NTOK * DM * 4);
    char* xzraw = (char*)alloc((size_t)NTOK * 2 * DI * 2);
    char* ucraw = (char*)alloc((size_t)NTOK * DI * 2);
    float* W96  = (float*)alloc((size_t)NTOK * 96 * 4);
    char* dtraw = (char*)alloc((size_t)NTOK * DI * 4);
    float* Hout = (float*)alloc((size_t)BB * DI * NC * DS * 4);
    float* Hin  = (float*)alloc((size_t)BB * DI * NC * DS * 4);
    float* Stot = (float*)alloc((size_t)BB * DI * NC * 4);
    float* top_w  = (float*)alloc(NTOK * 4);
    float* maskf  = (float*)alloc(NTOK * 4);
    float* pooled = (float*)alloc(BB * DM * 4);
    float* cntb   = (float*)alloc(64);
    int* top_idx  = (int*)alloc(NTOK * 4);
    int* perm     = (int*)alloc(NTOK * 4);
    int* cnt      = (int*)alloc(64);
    int* offs     = (int*)alloc(64);
    int* posc     = (int*)alloc(64);

    bf*    XZ   = (bf*)xzraw;
    bf*    UC   = (bf*)ucraw;
    float* DT   = (float*)dtraw;
    u16*   XS   = (u16*)ucraw;                                // X split2 [NTOK,2*DM]
    u16*   DTS  = (u16*)xzraw;                                // DT split2 [NTOK,2*DI]
    float* H1   = (float*)xzraw;                              // expert hidden f32 [NTOK,HH]
    u16*   H1S  = (u16*)(xzraw + (size_t)NTOK * HH * 4);      // H1 split2 [NTOK,2*HH]
    float* MAM1 = (float*)ucraw;                              // mamba out f32 [NTOK,DM]
    float* MAM2 = (float*)xzraw;                              // moe out f32 [NTOK,DM]
    u16*   WB   = (u16*)dtraw;                                // weight split buffer
    u16*   WDT  = (u16*)Hin;                                  // dt_w split (0.5MB <= 4MB)
    u16*   W96S = (u16*)Hout;                                 // W96 split (1MB <= 4MB)

    embed_kernel<<<(NTOK * DM) / 256, 256, 0, stream>>>(tokens, emb, pos, X);

    for (int lay = 0; lay < NLAY; lay++) {
        const float* in_w_l   = in_w   + (size_t)lay * 2 * DI * DM;
        const float* conv_w_l = conv_w + (size_t)lay * DI * DC;
        const float* conv_b_l = conv_b + (size_t)lay * DI;
        const float* xp_w_l   = xp_w   + (size_t)lay * 96 * DI;
        const float* dt_w_l   = dt_w   + (size_t)lay * DI * DTR;
        const float* dt_b_l   = dt_b   + (size_t)lay * DI;
        const float* A_log_l  = A_log  + (size_t)lay * DI * DS;
        const float* D_ssm_l  = D_ssm  + (size_t)lay * DI;
        const float* out_w_l  = out_w  + (size_t)lay * DM * DI;
        const float* gate_w_l = gate_w + (size_t)lay * NE * DM;
        const float* gate_b_l = gate_b + (size_t)lay * NE;
        const float* e_w1_l   = e_w1   + (size_t)lay * NE * HH * DM;
        const float* e_b1_l   = e_b1   + (size_t)lay * NE * HH;
        const float* e_w2_l   = e_w2   + (size_t)lay * NE * DM * HH;
        const float* e_b2_l   = e_b2   + (size_t)lay * NE * DM;

        // in_proj: XZ[4096,4096] = X @ in_w^T  (3-term split, numerics == old)
        split2_kernel<<<(NTOK * DM) / 1024, 256, 0, stream>>>(X, DM, XS, DM);
        split2_kernel<<<(2 * DI * DM) / 1024, 256, 0, stream>>>(in_w_l, DM, WB, DM);
        gemm_s<bf, 3, 128><<<dim3(32, 32, 1), 256, 0, stream>>>(
            XS, 2 * DM, WB, 2 * DM, XZ, 2 * DI, NTOK, 2 * DI, DM / 32,
            nullptr, 0, nullptr, nullptr, nullptr, 0, nullptr, 0, 0, 0, 0);

        // depthwise conv + silu -> UC (overwrites XS; in_proj already consumed it)
        conv_kernel<<<(NTOK * DI) / 256, 256, 0, stream>>>(XZ, conv_w_l, conv_b_l, UC);

        // x_proj: W96[4096,96] = UC @ xp_w^T  (A plain bf16; split-K x8, atomic)
        zerof4_kernel<<<(NTOK * 96) / 1024, 256, 0, stream>>>((float4*)W96);
        split2_kernel<<<(96 * DI) / 1024, 256, 0, stream>>>(xp_w_l, DI, WB, DI);
        gemm_s<float, 2, 128><<<dim3(1, 32, 8), 256, 0, stream>>>(
            (const u16*)UC, DI, WB, 2 * DI, W96, 96, NTOK, 96, DI / 32,
            nullptr, 0, nullptr, nullptr, nullptr, 0, nullptr, 0, 0, (DI / 32) / 8, 1);

        // dt_proj + softplus: DT = softplus(W96[:, :64] @ dt_w^T + dt_b)
        split2_kernel<<<(DI * DTR) / 1024, 256, 0, stream>>>(dt_w_l, DTR, WDT, DTR);
        split2_kernel<<<(NTOK * DTR) / 1024, 256, 0, stream>>>(W96, 96, W96S, DTR);
        gemm_s<float, 3, 128><<<dim3(16, 32, 1), 256, 0, stream>>>(
            W96S, 2 * DTR, WDT, 2 * DTR, DT, DI, NTOK, DI, DTR / 32,
            dt_b_l, 1, nullptr, nullptr, nullptr, 0, nullptr, 0, 0, 0, 0);

        // chunked scan: phase0 -> combine -> phase1 (writes gated y f32 over DT)
        scan_chunk<0><<<dim3(DI / 256, NC, BB), 256, 0, stream>>>(
            UC, DT, W96, XZ, A_log_l, D_ssm_l, Hout, Stot, nullptr);
        scan_combine<<<(BB * DI * DS) / 256, 256, 0, stream>>>(Hout, Stot, A_log_l, Hin);
        scan_chunk<1><<<dim3(DI / 256, NC, BB), 256, 0, stream>>>(
            UC, DT, W96, XZ, A_log_l, D_ssm_l, Hout, Stot, Hin);

        // out_proj: MAM1[4096,1024] = DT @ out_w^T  (DTS overlays dead XZ; then
        // out_w split overlays dead DT; MAM1 overlays dead UC)
        split2_kernel<<<(NTOK * DI) / 1024, 256, 0, stream>>>(DT, DI, DTS, DI);
        split2_kernel<<<(DM * DI) / 1024, 256, 0, stream>>>(out_w_l, DI, WB, DI);
        gemm_s<float, 3, 64><<<dim3(16, 32, 1), 256, 0, stream>>>(
            DTS, 2 * DI, WB, 2 * DI, MAM1, DM, NTOK, DM, DI / 32,
            nullptr, 0, nullptr, nullptr, nullptr, 0, nullptr, 0, 0, 0, 0);

        // x += LN1(MAM1)
        ln_residual_kernel<<<NTOK, 256, 0, stream>>>(X, MAM1, ln1_g + lay * DM, ln1_b + lay * DM);

        // MoE routing
        zero8_kernel<<<1, 32, 0, stream>>>(cnt);
        gate_kernel<<<NTOK, 64, 0, stream>>>(X, gate_w_l, gate_b_l, top_idx, top_w, cnt);
        offsets_kernel<<<1, 1, 0, stream>>>(cnt, offs, posc);
        scatter_kernel<<<NTOK / 256, 256, 0, stream>>>(top_idx, offs, posc, perm);

        // expert GEMM1: H1 = relu(X[perm] @ w1[e]^T + b1[e])
        split2_kernel<<<(NTOK * DM) / 1024, 256, 0, stream>>>(X, DM, XS, DM);
        split2_kernel<<<((size_t)NE * HH * DM) / 1024, 256, 0, stream>>>(e_w1_l, DM, WB, DM);
        gemm_s<float, 3, 64><<<dim3(16, 32, NE), 256, 0, stream>>>(
            XS, 2 * DM, WB, 2 * DM, H1, HH, NTOK, HH, DM / 32,
            e_b1_l, 2, cnt, offs, perm, 1, nullptr,
            (long long)HH * 2 * DM, (long long)HH, 0, 0);

        // expert GEMM2: MAM2[token] = top_w * (H1 @ w2[e]^T + b2[e])
        split2_kernel<<<(NTOK * HH) / 1024, 256, 0, stream>>>(H1, HH, H1S, HH);
        split2_kernel<<<((size_t)NE * DM * HH) / 1024, 256, 0, stream>>>(e_w2_l, HH, WB, HH);
        gemm_s<float, 3, 64><<<dim3(16, 32, NE), 256, 0, stream>>>(
            H1S, 2 * HH, WB, 2 * HH, MAM2, DM, NTOK, DM, HH / 32,
            e_b2_l, 0, cnt, offs, perm, 2, top_w,
            (long long)DM * 2 * HH, (long long)DM, 0, 0);

        // x += LN2(MAM2)
        ln_residual_kernel<<<NTOK, 256, 0, stream>>>(X, MAM2, ln2_g + lay * DM, ln2_b + lay * DM);
    }

    // pooling + head
    rowmask_kernel<<<NTOK, 256, 0, stream>>>(X, maskf);
    cntb_kernel<<<BB, 256, 0, stream>>>(maskf, cntb);
    pooled_kernel<<<dim3(DM / 256, BB, 1), 256, 0, stream>>>(X, maskf, cntb, pooled);
    head_kernel<<<BB, 128, 0, stream>>>(pooled, fc1_w, fc1_b, fc2_w, fc2_b, outp);
}

// Round 2
// 1802.888 us; speedup vs baseline: 1.3908x; 1.0436x over previous
//
#include <hip/hip_runtime.h>
#include <hip/hip_bf16.h>

using bf = __hip_bfloat16;
typedef unsigned short u16;

// Model dims
#define V_   32000
#define DM   1024
#define LQ   1024
#define BB   4
#define NLAY 2
#define NE   8
#define HH   1024
#define DS   16
#define DC   4
#define DI   2048
#define DTR  64
#define NTOK (BB*LQ)   // 4096

// scan chunking
#define NC 16
#define CL (LQ/NC)     // 64

typedef __attribute__((ext_vector_type(8))) short s8v;
typedef __attribute__((ext_vector_type(4))) float f4v;

__device__ inline float tofl(float x) { return x; }
__device__ inline float tofl(bf x) { return __bfloat162float(x); }

template<typename T> __device__ inline T fromf(float v);
template<> __device__ inline float fromf<float>(float v) { return v; }
template<> __device__ inline bf fromf<bf>(float v) { return __float2bfloat16(v); }

__device__ inline u16 f2bfu(float x) {
    bf h = __float2bfloat16(x);
    return __builtin_bit_cast(u16, h);
}
__device__ inline float bfu2f(u16 u) {
    bf h = __builtin_bit_cast(bf, u);
    return __bfloat162float(h);
}

__device__ inline f4v mfma16(s8v a, s8v b, f4v c) {
    return __builtin_amdgcn_mfma_f32_16x16x32_bf16(a, b, c, 0, 0, 0);
}

// async global->LDS, 16B per lane. LDS dest is wave-uniform base + lane*16;
// global src is per-lane.
__device__ __forceinline__ void gl2lds16(const u16* g, u16* l) {
    __builtin_amdgcn_global_load_lds(
        (const __attribute__((address_space(1))) unsigned int*)g,
        (__attribute__((address_space(3))) unsigned int*)l, 16, 0, 0);
}

// ---------------------------------------------------------------------------
// split2: f32 [R,K] (row stride ldin) -> bf16 [R,2K]; per 32-col block b:
// out[r][b*64 + j]   = bf16(x)          (hi)
// out[r][b*64+32+ j] = bf16(x - hi)     (lo)
// ---------------------------------------------------------------------------
__global__ __launch_bounds__(256) void split2_kernel(
    const float* __restrict__ in, int ldin,
    u16* __restrict__ out, int K)
{
    int id = blockIdx.x * 256 + threadIdx.x;
    int e4 = id * 4;
    int r = e4 / K;
    int k = e4 - r * K;
    float4 v = *(const float4*)(in + (size_t)r * ldin + k);
    int b = k >> 5, j = k & 31;
    ushort4 hi, lo;
    hi.x = f2bfu(v.x); lo.x = f2bfu(v.x - bfu2f(hi.x));
    hi.y = f2bfu(v.y); lo.y = f2bfu(v.y - bfu2f(hi.y));
    hi.z = f2bfu(v.z); lo.z = f2bfu(v.z - bfu2f(hi.z));
    hi.w = f2bfu(v.w); lo.w = f2bfu(v.w - bfu2f(hi.w));
    u16* o = out + (size_t)r * (2 * K) + b * 64 + j;
    *(ushort4*)o = hi;
    *(ushort4*)(o + 32) = lo;
}

__global__ __launch_bounds__(256) void zerof4_kernel(float4* __restrict__ p) {
    p[(size_t)blockIdx.x * 256 + threadIdx.x] = make_float4(0.f, 0.f, 0.f, 0.f);
}

// ---------------------------------------------------------------------------
// Deep-pipelined 3-term split GEMM (in_proj shape): C[M,N] = A @ B^T.
// A [M,2K] split2, B [N,2K] split2, C bf16.
// 256x128 tile, 8 waves (512 thr), BK=32 (64 u16 hi|lo), 3 LDS buffers,
// 2-step-ahead global_load_lds prefetch, counted vmcnt(6) (never 0 in
// steady state), raw s_barrier + sched_barrier fences, setprio around MFMA.
// LDS chunk-XOR swizzle: linear LDS dest, inverse-swizzled global source,
// swizzled ds_read (rule: both-sides-or-neither with global_load_lds).
// Requires M%256==0, N%128==0 (no guards).
// Per-acc-element MFMA order: q ascending; hi*hi, hi*lo, lo*hi — identical
// numerics to gemm_s<...,3,...>.
// ---------------------------------------------------------------------------
__global__ __launch_bounds__(512) void gemm_pipe3(
    const u16* __restrict__ A, int lda,
    const u16* __restrict__ Bw, int ldb,
    bf* __restrict__ C, int ldc,
    int K32)
{
    __shared__ u16 LA[3][256 * 64];   // 96 KB
    __shared__ u16 LB[3][128 * 64];   // 48 KB

    int t = threadIdx.x, lane = t & 63, wv = t >> 6;
    int m0 = blockIdx.y * 256, n0 = blockIdx.x * 128;
    int wm = (wv >> 1) * 64, wn = (wv & 1) * 64;
    int fr = lane & 15, kq = lane >> 4;

    // staging lane geometry: lane covers row (i>>3) of an 8-row group,
    // LDS chunk (i&7); fetches global chunk (i&7)^(row&7) so that a
    // swizzled read LDS[R][g^(R&7)] returns global chunk g.
    int lrow8 = lane >> 3;
    int lchunk = (lane & 7) ^ lrow8;
    const u16* Abase = A + (size_t)(m0 + wv * 32 + lrow8) * lda + lchunk * 8;
    const u16* Bbase = Bw + (size_t)(n0 + wv * 16 + lrow8) * ldb + lchunk * 8;

    f4v acc[4][4];
#pragma unroll
    for (int i = 0; i < 4; i++)
#pragma unroll
        for (int j = 0; j < 4; j++) acc[i][j] = 0.f;

    auto stage = [&](int q, int s) {
        const u16* ap = Abase + (size_t)q * 64;
#pragma unroll
        for (int j = 0; j < 4; j++)
            gl2lds16(ap + (size_t)(j * 8) * lda, &LA[s][(wv * 32 + j * 8) * 64]);
        const u16* bp = Bbase + (size_t)q * 64;
#pragma unroll
        for (int j = 0; j < 2; j++)
            gl2lds16(bp + (size_t)(j * 8) * ldb, &LB[s][(wv * 16 + j * 8) * 64]);
    };

    stage(0, 0);            // 6 loads
    stage(1, 1);            // 6 loads

    for (int q = 0; q < K32; ++q) {
        int s = q % 3;
        // wait for this step's tile (6 newer loads may stay in flight)
        if (q + 1 < K32) asm volatile("s_waitcnt vmcnt(6)" ::: "memory");
        else             asm volatile("s_waitcnt vmcnt(0)" ::: "memory");
        __builtin_amdgcn_sched_barrier(0);
        __builtin_amdgcn_s_barrier();
        __builtin_amdgcn_sched_barrier(0);

        if (q + 2 < K32) stage(q + 2, (q + 2) % 3);

        s8v ah[4], al[4], bh[4], bl[4];
#pragma unroll
        for (int mi = 0; mi < 4; mi++) {
            int R = wm + mi * 16 + fr;
            int c = kq ^ (R & 7);
            ah[mi] = *(const s8v*)&LA[s][R * 64 + c * 8];
            al[mi] = *(const s8v*)&LA[s][R * 64 + (c ^ 4) * 8];
        }
#pragma unroll
        for (int ni = 0; ni < 4; ni++) {
            int R = wn + ni * 16 + fr;
            int c = kq ^ (R & 7);
            bh[ni] = *(const s8v*)&LB[s][R * 64 + c * 8];
            bl[ni] = *(const s8v*)&LB[s][R * 64 + (c ^ 4) * 8];
        }
        __builtin_amdgcn_s_setprio(1);
#pragma unroll
        for (int mi = 0; mi < 4; mi++)
#pragma unroll
            for (int ni = 0; ni < 4; ni++) {
                acc[mi][ni] = mfma16(ah[mi], bh[ni], acc[mi][ni]);   // hi*hi
                acc[mi][ni] = mfma16(ah[mi], bl[ni], acc[mi][ni]);   // hi*lo
                acc[mi][ni] = mfma16(al[mi], bh[ni], acc[mi][ni]);   // lo*hi
            }
        __builtin_amdgcn_s_setprio(0);
        __builtin_amdgcn_sched_barrier(0);
    }

    // epilogue: C row = (lane>>4)*4 + reg, col = lane&15
#pragma unroll
    for (int mi = 0; mi < 4; mi++) {
#pragma unroll
        for (int r4 = 0; r4 < 4; r4++) {
            int m = m0 + wm + mi * 16 + kq * 4 + r4;
#pragma unroll
            for (int ni = 0; ni < 4; ni++) {
                int n = n0 + wn + ni * 16 + fr;
                C[(size_t)m * ldc + n] = __float2bfloat16(acc[mi][ni][r4]);
            }
        }
    }
}

// ---------------------------------------------------------------------------
// MFMA GEMM on pre-split bf16 operands (2-barrier structure; small/odd shapes
// and expert gather/scatter). See round-1 comments. SPLITOUT=1: epilogue
// writes split2-format u16 pairs (C is u16*, ldc in u16 units).
// ---------------------------------------------------------------------------
template<typename TC, int TERMS, int BN, int SPLITOUT = 0>
__global__ __launch_bounds__(256, 3) void gemm_s(
    const u16* __restrict__ A, int lda,
    const u16* __restrict__ Bw, int ldb,
    TC* __restrict__ C, int ldc,
    int M, int N, int K32,
    const float* __restrict__ bias, int epi,        // 0 none, 1 softplus, 2 relu
    const int* __restrict__ cnt, const int* __restrict__ offs,
    const int* __restrict__ perm, int permmode,
    const float* __restrict__ scale,
    long long strideB_e, long long stride_bias_e,
    int nqz, int atomic_out)
{
    int zb = blockIdx.z;
    int Meff = M, rowoff = 0;
    int q0 = 0, q1 = K32;
    if (cnt) {
        Meff = cnt[zb];
        rowoff = offs[zb];
        Bw += (size_t)zb * strideB_e;
        if (bias) bias += (size_t)zb * stride_bias_e;
    } else if (nqz) {
        q0 = zb * nqz; q1 = q0 + nqz;
    }
    int m0 = blockIdx.y * 128;
    if (m0 >= Meff) return;
    int n0 = blockIdx.x * BN;

    constexpr int MI  = (BN == 128) ? 4 : 2;
    constexpr int NBR = BN / 64;                 // B staging rounds

    __shared__ u16 AsH[128 * 32];
    __shared__ u16 AsL[(TERMS == 3) ? 128 * 32 : 8];
    __shared__ u16 BsH[BN * 32];
    __shared__ u16 BsL[BN * 32];

    int t = threadIdx.x, lane = t & 63, wv = t >> 6;
    int wm = (BN == 128) ? (wv & 1) * 64 : wv * 32;
    int wn = (BN == 128) ? (wv >> 1) * 64 : 0;
    int fr = lane & 15, kq = lane >> 4;
    int chunk = lane & 3;

    int arow[2], brow[2];
#pragma unroll
    for (int r = 0; r < 2; r++) {
        int m = m0 + r * 64 + wv * 16 + (lane >> 2);
        int ar = rowoff + ((m < Meff) ? m : 0);
        arow[r] = (permmode & 1) ? perm[ar] : ar;
    }
#pragma unroll
    for (int r = 0; r < NBR; r++) {
        int n = n0 + r * 64 + wv * 16 + (lane >> 2);
        brow[r] = (n < N) ? n : 0;
    }

    f4v acc[MI][4];
#pragma unroll
    for (int i = 0; i < MI; i++)
#pragma unroll
        for (int j = 0; j < 4; j++) acc[i][j] = 0.f;

    for (int q = q0; q < q1; ++q) {
        size_t acol = (TERMS == 3) ? ((size_t)q * 64 + chunk * 8)
                                   : ((size_t)q * 32 + chunk * 8);
        size_t bcol = (size_t)q * 64 + chunk * 8;
#pragma unroll
        for (int r = 0; r < 2; r++) {
            const u16* ap = A + (size_t)arow[r] * lda + acol;
            gl2lds16(ap, &AsH[(r * 64 + wv * 16) * 32]);
            if constexpr (TERMS == 3)
                gl2lds16(ap + 32, &AsL[(r * 64 + wv * 16) * 32]);
        }
#pragma unroll
        for (int r = 0; r < NBR; r++) {
            const u16* bp = Bw + (size_t)brow[r] * ldb + bcol;
            gl2lds16(bp, &BsH[(r * 64 + wv * 16) * 32]);
            gl2lds16(bp + 32, &BsL[(r * 64 + wv * 16) * 32]);
        }
        __syncthreads();

        s8v ahf[MI], bhf[4], blf[4];
#pragma unroll
        for (int mi = 0; mi < MI; mi++)
            ahf[mi] = *(const s8v*)&AsH[(wm + mi * 16 + fr) * 32 + kq * 8];
#pragma unroll
        for (int ni = 0; ni < 4; ni++)
            bhf[ni] = *(const s8v*)&BsH[(wn + ni * 16 + fr) * 32 + kq * 8];
#pragma unroll
        for (int ni = 0; ni < 4; ni++)
            blf[ni] = *(const s8v*)&BsL[(wn + ni * 16 + fr) * 32 + kq * 8];
#pragma unroll
        for (int mi = 0; mi < MI; mi++)
#pragma unroll
            for (int ni = 0; ni < 4; ni++) {
                acc[mi][ni] = mfma16(ahf[mi], bhf[ni], acc[mi][ni]);
                acc[mi][ni] = mfma16(ahf[mi], blf[ni], acc[mi][ni]);
            }
        if constexpr (TERMS == 3) {
            s8v alf[MI];
#pragma unroll
            for (int mi = 0; mi < MI; mi++)
                alf[mi] = *(const s8v*)&AsL[(wm + mi * 16 + fr) * 32 + kq * 8];
#pragma unroll
            for (int mi = 0; mi < MI; mi++)
#pragma unroll
                for (int ni = 0; ni < 4; ni++)
                    acc[mi][ni] = mfma16(alf[mi], bhf[ni], acc[mi][ni]);
        }
        __syncthreads();
    }

#pragma unroll
    for (int mi = 0; mi < MI; mi++) {
#pragma unroll
        for (int r4 = 0; r4 < 4; r4++) {
            int m = m0 + wm + mi * 16 + kq * 4 + r4;
            if (m >= Meff) continue;
            long long crow;
            float sc = 1.f;
            int ar = rowoff + m;
            if (permmode & 2) { int tok = perm[ar]; crow = tok; sc = scale[tok]; }
            else crow = ar;
#pragma unroll
            for (int ni = 0; ni < 4; ni++) {
                int n = n0 + wn + ni * 16 + fr;
                if (n >= N) continue;
                float v = acc[mi][ni][r4];
                if (bias) v += bias[n];
                if (epi == 1) v = (v > 20.f) ? v : log1pf(__expf(v));
                else if (epi == 2) v = fmaxf(v, 0.f);
                v *= sc;
                if constexpr (SPLITOUT) {
                    u16 hi = f2bfu(v);
                    u16 lo = f2bfu(v - bfu2f(hi));
                    size_t o = (size_t)crow * ldc + ((n >> 5) << 6) + (n & 31);
                    ((u16*)C)[o] = hi;
                    ((u16*)C)[o + 32] = lo;
                } else {
                    long long idx = crow * ldc + n;
                    if constexpr (sizeof(TC) == 4) {
                        if (atomic_out) atomicAdd((float*)C + idx, v);
                        else C[idx] = fromf<TC>(v);
                    } else {
                        C[idx] = fromf<TC>(v);
                    }
                }
            }
        }
    }
}

// ---------------------------------------------------------------------------
__global__ __launch_bounds__(256) void embed_kernel(
    const int* __restrict__ tokens, const float* __restrict__ emb,
    const float* __restrict__ pos, float* __restrict__ X)
{
    int id = blockIdx.x * 256 + threadIdx.x;   // NTOK*DM threads
    int r = id >> 10, d = id & 1023;
    int l = r & (LQ - 1);
    int tok = tokens[r];
    X[id] = emb[(size_t)tok * DM + d] + pos[l * DM + d];
}

// causal depthwise conv (DC=4) + SiLU.  u lives in XZ[:, 0:DI], row stride 2*DI
__global__ __launch_bounds__(256) void conv_kernel(
    const bf* __restrict__ XZ, const float* __restrict__ cw,
    const float* __restrict__ cb, bf* __restrict__ UC)
{
    int id = blockIdx.x * 256 + threadIdx.x;   // NTOK*DI threads
    int d = id & (DI - 1);
    int r = id >> 11;
    int l = r & (LQ - 1);
    float acc = cb[d];
#pragma unroll
    for (int j = 0; j < DC; j++) {
        int ll = l - (DC - 1) + j;
        if (ll >= 0)
            acc += tofl(XZ[(size_t)(r - (DC - 1) + j) * (2 * DI) + d]) * cw[d * DC + j];
    }
    float sg = 1.f / (1.f + __expf(-acc));
    UC[id] = __float2bfloat16(acc * sg);
}

// ---------------------------------------------------------------------------
// Chunked parallel scan with next-step u/dt prefetch.
// ---------------------------------------------------------------------------
template<int PHASE>
__global__ __launch_bounds__(256) void scan_chunk(
    const bf* __restrict__ UC, float* __restrict__ DT,
    const float* __restrict__ W96, const bf* __restrict__ XZ,
    const float* __restrict__ A_log, const float* __restrict__ D_ssm,
    float* __restrict__ Hout, float* __restrict__ Stot,
    const float* __restrict__ Hin)
{
    int d = blockIdx.x * 256 + threadIdx.x;    // DI/256 blocks in x
    int c = blockIdx.y, b = blockIdx.z;
    float A[DS];
#pragma unroll
    for (int n = 0; n < DS; n++) A[n] = -__expf(A_log[d * DS + n]);
    float Dv = D_ssm[d];
    float h[DS];
    size_t hbase = ((size_t)(b * DI + d) * NC + c) * DS;
    if (PHASE == 0) {
#pragma unroll
        for (int n = 0; n < DS; n++) h[n] = 0.f;
    } else {
#pragma unroll
        for (int n = 0; n < DS; n += 4)
            *(float4*)&h[n] = *(const float4*)&Hin[hbase + n];
    }
    float S = 0.f;

    size_t rowb = (size_t)((b << 10) + c * CL);
    float u_c = tofl(UC[rowb * DI + d]);
    float dt_c = DT[rowb * DI + d];

    for (int t = 0; t < CL; t++) {
        size_t r = rowb + t;
        float u_n = 0.f, dt_n = 0.f;
        if (t + 1 < CL) {                       // prefetch next step
            u_n = tofl(UC[(r + 1) * DI + d]);
            dt_n = DT[(r + 1) * DI + d];
        }
        float du = dt_c * u_c;
        if (PHASE == 0) S += dt_c;
        float y = 0.f;
#pragma unroll
        for (int n = 0; n < DS; n++) {
            float Bv = W96[r * 96 + DTR + n];
            h[n] = __expf(dt_c * A[n]) * h[n] + du * Bv;
            if (PHASE == 1) y += h[n] * W96[r * 96 + DTR + DS + n];
        }
        if (PHASE == 1) {
            float z = tofl(XZ[r * (2 * DI) + DI + d]);
            float sil = z / (1.f + __expf(-z));
            DT[r * DI + d] = (y + u_c * Dv) * sil;
        }
        u_c = u_n; dt_c = dt_n;
    }
    if (PHASE == 0) {
#pragma unroll
        for (int n = 0; n < DS; n += 4)
            *(float4*)&Hout[hbase + n] = *(const float4*)&h[n];
        Stot[(size_t)(b * DI + d) * NC + c] = S;
    }
}

__global__ __launch_bounds__(256) void scan_combine(
    const float* __restrict__ Hout, const float* __restrict__ Stot,
    const float* __restrict__ A_log, float* __restrict__ Hin)
{
    int id = blockIdx.x * 256 + threadIdx.x;   // BB*DI*DS = 131072 threads
    int n = id & (DS - 1);
    int d = (id >> 4) & (DI - 1);
    int b = id >> 15;
    float A = -__expf(A_log[d * DS + n]);
    float h = 0.f;
    size_t base = (size_t)(b * DI + d) * NC * DS + n;
    size_t sbase = (size_t)(b * DI + d) * NC;
    for (int c = 0; c < NC; c++) {
        Hin[base + (size_t)c * DS] = h;
        h = __expf(A * Stot[sbase + c]) * h + Hout[base + (size_t)c * DS];
    }
}

// ---------------------------------------------------------------------------
// LN(src) * g + b added into f32 residual stream X.  One block per row.
// Optional: emit split2(updated X) into xs; zero cnt via block 0.
__global__ __launch_bounds__(256) void ln_residual_kernel(
    float* __restrict__ X, const float* __restrict__ src,
    const float* __restrict__ g, const float* __restrict__ b,
    u16* __restrict__ xs, int* __restrict__ cntz)
{
    int row = blockIdx.x, tid = threadIdx.x;
    __shared__ float red[256];
    float v[4];
    float s = 0.f;
#pragma unroll
    for (int i = 0; i < 4; i++) { v[i] = src[(size_t)row * DM + tid + 256 * i]; s += v[i]; }
    red[tid] = s; __syncthreads();   // after this barrier all src reads are done
    for (int o = 128; o > 0; o >>= 1) { if (tid < o) red[tid] += red[tid + o]; __syncthreads(); }
    float mean = red[0] * (1.f / DM);
    __syncthreads();
    float vs = 0.f;
#pragma unroll
    for (int i = 0; i < 4; i++) { float dd = v[i] - mean; vs += dd * dd; }
    red[tid] = vs; __syncthreads();
    for (int o = 128; o > 0; o >>= 1) { if (tid < o) red[tid] += red[tid + o]; __syncthreads(); }
    float rstd = rsqrtf(red[0] * (1.f / DM) + 1e-5f);
#pragma unroll
    for (int i = 0; i < 4; i++) {
        int c = tid + 256 * i;
        float nx = X[(size_t)row * DM + c] + (v[i] - mean) * rstd * g[c] + b[c];
        X[(size_t)row * DM + c] = nx;
        if (xs) {
            u16 hi = f2bfu(nx);
            u16 lo = f2bfu(nx - bfu2f(hi));
            size_t o2 = (size_t)row * (2 * DM) + ((c >> 5) << 6) + (c & 31);
            xs[o2] = hi;
            xs[o2 + 32] = lo;
        }
    }
    if (cntz && row == 0 && tid < 8) cntz[tid] = 0;
}

// gate: logits -> softmax max/argmax -> top_idx/top_w + per-expert counts
__global__ __launch_bounds__(64) void gate_kernel(
    const float* __restrict__ X, const float* __restrict__ gw, const float* __restrict__ gb,
    int* __restrict__ top_idx, float* __restrict__ top_w, int* __restrict__ cnt)
{
    int n = blockIdx.x;
    int lane = threadIdx.x;
    float acc[NE] = {};
    for (int k = lane; k < DM; k += 64) {
        float xv = X[(size_t)n * DM + k];
#pragma unroll
        for (int e = 0; e < NE; e++) acc[e] += xv * gw[e * DM + k];
    }
#pragma unroll
    for (int e = 0; e < NE; e++)
        for (int o = 32; o > 0; o >>= 1) acc[e] += __shfl_down(acc[e], o);
    if (lane == 0) {
        float logits[NE];
        float best = -1e30f; int bi = 0;
#pragma unroll
        for (int e = 0; e < NE; e++) {
            logits[e] = acc[e] + gb[e];
            if (logits[e] > best) { best = logits[e]; bi = e; }
        }
        float s = 0.f;
#pragma unroll
        for (int e = 0; e < NE; e++) s += __expf(logits[e] - best);
        top_idx[n] = bi;
        top_w[n] = 1.f / s;
        atomicAdd(&cnt[bi], 1);
    }
}

__global__ void offsets_kernel(const int* __restrict__ cnt, int* __restrict__ offs, int* __restrict__ pos)
{
    if (threadIdx.x == 0) {
        int a = 0;
        for (int e = 0; e < NE; e++) { offs[e] = a; a += cnt[e]; pos[e] = 0; }
        offs[NE] = a;
    }
}

__global__ __launch_bounds__(256) void scatter_kernel(
    const int* __restrict__ top_idx, const int* __restrict__ offs,
    int* __restrict__ pos, int* __restrict__ perm)
{
    int n = blockIdx.x * 256 + threadIdx.x;
    if (n >= NTOK) return;
    int e = top_idx[n];
    int slot = atomicAdd(&pos[e], 1);
    perm[offs[e] + slot] = n;
}

__global__ __launch_bounds__(256) void rowmask_kernel(const float* __restrict__ X, float* __restrict__ maskf)
{
    int row = blockIdx.x, tid = threadIdx.x;
    __shared__ float red[256];
    float s = 0.f;
    for (int i = tid; i < DM; i += 256) s += X[(size_t)row * DM + i];
    red[tid] = s; __syncthreads();
    for (int o = 128; o > 0; o >>= 1) { if (tid < o) red[tid] += red[tid + o]; __syncthreads(); }
    if (tid == 0) maskf[row] = (red[0] != 0.f) ? 1.f : 0.f;
}

__global__ __launch_bounds__(256) void cntb_kernel(const float* __restrict__ maskf, float* __restrict__ cntb)
{
    int b = blockIdx.x, tid = threadIdx.x;
    __shared__ float red[256];
    float s = 0.f;
    for (int i = tid; i < LQ; i += 256) s += maskf[b * LQ + i];
    red[tid] = s; __syncthreads();
    for (int o = 128; o > 0; o >>= 1) { if (tid < o) red[tid] += red[tid + o]; __syncthreads(); }
    if (tid == 0) cntb[b] = red[0];
}

__global__ __launch_bounds__(256) void pooled_kernel(
    const float* __restrict__ X, const float* __restrict__ maskf,
    const float* __restrict__ cntb, float* __restrict__ pooled)
{
    int d = blockIdx.x * 256 + threadIdx.x;
    int b = blockIdx.y;
    float s = 0.f;
    for (int l = 0; l < LQ; l++)
        s += X[(size_t)((b << 10) + l) * DM + d] * maskf[(b << 10) + l];
    pooled[b * DM + d] = s / fmaxf(cntb[b], 1.f);
}

__global__ __launch_bounds__(128) void head_kernel(
    const float* __restrict__ pooled,
    const float* __restrict__ fc1w, const float* __restrict__ fc1b,
    const float* __restrict__ fc2w, const float* __restrict__ fc2b,
    float* __restrict__ out)
{
    int b = blockIdx.x;
    int j = threadIdx.x;   // 128
    __shared__ float hbuf[128];
    float acc = fc1b[j];
    for (int k = 0; k < DM; k++) acc += pooled[b * DM + k] * fc1w[j * DM + k];
    hbuf[j] = fmaxf(acc, 0.f);
    __syncthreads();
    if (j < 2) {
        float o = fc2b[j];
        for (int k = 0; k < 128; k++) o += hbuf[k] * fc2w[j * 128 + k];
        out[b * 2 + j] = o;
    }
}

// ---------------------------------------------------------------------------
extern "C" void kernel_launch(void* const* d_in, const int* in_sizes, int n_in,
                              void* d_out, int out_size, void* d_ws, size_t ws_size,
                              hipStream_t stream)
{
    const int*   tokens = (const int*)d_in[0];
    const float* emb    = (const float*)d_in[1];
    const float* pos    = (const float*)d_in[2];
    const float* in_w   = (const float*)d_in[3];
    const float* conv_w = (const float*)d_in[4];
    const float* conv_b = (const float*)d_in[5];
    const float* xp_w   = (const float*)d_in[6];
    const float* dt_w   = (const float*)d_in[7];
    const float* dt_b   = (const float*)d_in[8];
    const float* A_log  = (const float*)d_in[9];
    const float* D_ssm  = (const float*)d_in[10];
    const float* out_w  = (const float*)d_in[11];
    const float* ln1_g  = (const float*)d_in[12];
    const float* ln1_b  = (const float*)d_in[13];
    const float* ln2_g  = (const float*)d_in[14];
    const float* ln2_b  = (const float*)d_in[15];
    const float* gate_w = (const float*)d_in[16];
    const float* gate_b = (const float*)d_in[17];
    const float* e_w1   = (const float*)d_in[18];
    const float* e_b1   = (const float*)d_in[19];
    const float* e_w2   = (const float*)d_in[20];
    const float* e_b2   = (const float*)d_in[21];
    const float* fc1_w  = (const float*)d_in[22];
    const float* fc1_b  = (const float*)d_in[23];
    const float* fc2_w  = (const float*)d_in[24];
    const float* fc2_b  = (const float*)d_in[25];
    float* outp = (float*)d_out;

    // workspace layout (~120 MB peak, heavy overlay reuse):
    //  xzraw (33.5MB): XZ -> DTS -> H1S(at +16MB) / MAM2(front)
    //  ucraw (16.8MB): XS -> UC -> MAM1/XS(ln1) -> XS(ln2)
    //  dtraw (33.5MB): weight-split buf -> DT -> weight-split buf (experts)
    //  Hout/Hin (8MB each): scan state; also W96S / dt_w-split scratch
    char* wsb = (char*)d_ws;
    size_t off = 0;
    auto alloc = [&](size_t bytes) { char* p = wsb + off; off += (bytes + 255) & ~(size_t)255; return p; };
    float* X    = (float*)alloc((size_t)NTOK * DM * 4);
    char* xzraw = (char*)alloc((size_t)NTOK * 2 * DI * 2);
    char* ucraw = (char*)alloc((size_t)NTOK * DI * 2);
    float* W96  = (float*)alloc((size_t)NTOK * 96 * 4);
    char* dtraw = (char*)alloc((size_t)NTOK * DI * 4);
    float* Hout = (float*)alloc((size_t)BB * DI * NC * DS * 4);
    float* Hin  = (float*)alloc((size_t)BB * DI * NC * DS * 4);
    float* Stot = (float*)alloc((size_t)BB * DI * NC * 4);
    float* top_w  = (float*)alloc(NTOK * 4);
    float* maskf  = (float*)alloc(NTOK * 4);
    float* pooled = (float*)alloc(BB * DM * 4);
    float* cntb   = (float*)alloc(64);
    int* top_idx  = (int*)alloc(NTOK * 4);
    int* perm     = (int*)alloc(NTOK * 4);
    int* cnt      = (int*)alloc(64);
    int* offs     = (int*)alloc(64);
    int* posc     = (int*)alloc(64);

    bf*    XZ   = (bf*)xzraw;
    bf*    UC   = (bf*)ucraw;
    float* DT   = (float*)dtraw;
    u16*   XS   = (u16*)ucraw;                                // X split2 [NTOK,2*DM]
    u16*   DTS  = (u16*)xzraw;                                // DT split2 [NTOK,2*DI]
    u16*   H1S  = (u16*)(xzraw + (size_t)NTOK * HH * 4);      // H1 split2 [NTOK,2*HH]
    float* MAM1 = (float*)ucraw;                              // mamba out f32 [NTOK,DM]
    float* MAM2 = (float*)xzraw;                              // moe out f32 [NTOK,DM]
    u16*   WB   = (u16*)dtraw;                                // weight split buffer
    u16*   WDT  = (u16*)Hin;                                  // dt_w split (0.5MB <= 8MB)
    u16*   W96S = (u16*)Hout;                                 // W96 split (1MB <= 8MB)

    embed_kernel<<<(NTOK * DM) / 256, 256, 0, stream>>>(tokens, emb, pos, X);

    for (int lay = 0; lay < NLAY; lay++) {
        const float* in_w_l   = in_w   + (size_t)lay * 2 * DI * DM;
        const float* conv_w_l = conv_w + (size_t)lay * DI * DC;
        const float* conv_b_l = conv_b + (size_t)lay * DI;
        const float* xp_w_l   = xp_w   + (size_t)lay * 96 * DI;
        const float* dt_w_l   = dt_w   + (size_t)lay * DI * DTR;
        const float* dt_b_l   = dt_b   + (size_t)lay * DI;
        const float* A_log_l  = A_log  + (size_t)lay * DI * DS;
        const float* D_ssm_l  = D_ssm  + (size_t)lay * DI;
        const float* out_w_l  = out_w  + (size_t)lay * DM * DI;
        const float* gate_w_l = gate_w + (size_t)lay * NE * DM;
        const float* gate_b_l = gate_b + (size_t)lay * NE;
        const float* e_w1_l   = e_w1   + (size_t)lay * NE * HH * DM;
        const float* e_b1_l   = e_b1   + (size_t)lay * NE * HH;
        const float* e_w2_l   = e_w2   + (size_t)lay * NE * DM * HH;
        const float* e_b2_l   = e_b2   + (size_t)lay * NE * DM;

        // in_proj: XZ[4096,4096] = X @ in_w^T  (3-term split, deep pipeline)
        if (lay == 0)
            split2_kernel<<<(NTOK * DM) / 1024, 256, 0, stream>>>(X, DM, XS, DM);
        // (lay>0: XS was emitted by previous layer's LN2)
        split2_kernel<<<(2 * DI * DM) / 1024, 256, 0, stream>>>(in_w_l, DM, WB, DM);
        gemm_pipe3<<<dim3(2 * DI / 128, NTOK / 256, 1), 512, 0, stream>>>(
            XS, 2 * DM, WB, 2 * DM, XZ, 2 * DI, DM / 32);

        // depthwise conv + silu -> UC (overwrites XS; in_proj already consumed it)
        conv_kernel<<<(NTOK * DI) / 256, 256, 0, stream>>>(XZ, conv_w_l, conv_b_l, UC);

        // x_proj: W96[4096,96] = UC @ xp_w^T  (A plain bf16; split-K x8, atomic)
        zerof4_kernel<<<(NTOK * 96) / 1024, 256, 0, stream>>>((float4*)W96);
        split2_kernel<<<(96 * DI) / 1024, 256, 0, stream>>>(xp_w_l, DI, WB, DI);
        gemm_s<float, 2, 128><<<dim3(1, 32, 8), 256, 0, stream>>>(
            (const u16*)UC, DI, WB, 2 * DI, W96, 96, NTOK, 96, DI / 32,
            nullptr, 0, nullptr, nullptr, nullptr, 0, nullptr, 0, 0, (DI / 32) / 8, 1);

        // dt_proj + softplus: DT = softplus(W96[:, :64] @ dt_w^T + dt_b)
        split2_kernel<<<(DI * DTR) / 1024, 256, 0, stream>>>(dt_w_l, DTR, WDT, DTR);
        split2_kernel<<<(NTOK * DTR) / 1024, 256, 0, stream>>>(W96, 96, W96S, DTR);
        gemm_s<float, 3, 128><<<dim3(16, 32, 1), 256, 0, stream>>>(
            W96S, 2 * DTR, WDT, 2 * DTR, DT, DI, NTOK, DI, DTR / 32,
            dt_b_l, 1, nullptr, nullptr, nullptr, 0, nullptr, 0, 0, 0, 0);

        // chunked scan: phase0 -> combine -> phase1 (writes gated y f32 over DT)
        scan_chunk<0><<<dim3(DI / 256, NC, BB), 256, 0, stream>>>(
            UC, DT, W96, XZ, A_log_l, D_ssm_l, Hout, Stot, nullptr);
        scan_combine<<<(BB * DI * DS) / 256, 256, 0, stream>>>(Hout, Stot, A_log_l, Hin);
        scan_chunk<1><<<dim3(DI / 256, NC, BB), 256, 0, stream>>>(
            UC, DT, W96, XZ, A_log_l, D_ssm_l, Hout, Stot, Hin);

        // out_proj: MAM1[4096,1024] = DT @ out_w^T
        split2_kernel<<<(NTOK * DI) / 1024, 256, 0, stream>>>(DT, DI, DTS, DI);
        split2_kernel<<<(DM * DI) / 1024, 256, 0, stream>>>(out_w_l, DI, WB, DI);
        gemm_s<float, 3, 128><<<dim3(8, 32, 1), 256, 0, stream>>>(
            DTS, 2 * DI, WB, 2 * DI, MAM1, DM, NTOK, DM, DI / 32,
            nullptr, 0, nullptr, nullptr, nullptr, 0, nullptr, 0, 0, 0, 0);

        // x += LN1(MAM1); fused: emit XS = split2(updated X), zero cnt
        ln_residual_kernel<<<NTOK, 256, 0, stream>>>(
            X, MAM1, ln1_g + lay * DM, ln1_b + lay * DM, XS, cnt);

        // MoE routing
        gate_kernel<<<NTOK, 64, 0, stream>>>(X, gate_w_l, gate_b_l, top_idx, top_w, cnt);
        offsets_kernel<<<1, 1, 0, stream>>>(cnt, offs, posc);
        scatter_kernel<<<NTOK / 256, 256, 0, stream>>>(top_idx, offs, posc, perm);

        // expert GEMM1: H1S (split2 u16) = relu(X[perm] @ w1[e]^T + b1[e])
        split2_kernel<<<((size_t)NE * HH * DM) / 1024, 256, 0, stream>>>(e_w1_l, DM, WB, DM);
        gemm_s<u16, 3, 128, 1><<<dim3(8, 32, NE), 256, 0, stream>>>(
            XS, 2 * DM, WB, 2 * DM, H1S, 2 * HH, NTOK, HH, DM / 32,
            e_b1_l, 2, cnt, offs, perm, 1, nullptr,
            (long long)HH * 2 * DM, (long long)HH, 0, 0);

        // expert GEMM2: MAM2[token] = top_w * (H1 @ w2[e]^T + b2[e])
        split2_kernel<<<((size_t)NE * DM * HH) / 1024, 256, 0, stream>>>(e_w2_l, HH, WB, HH);
        gemm_s<float, 3, 128><<<dim3(8, 32, NE), 256, 0, stream>>>(
            H1S, 2 * HH, WB, 2 * HH, MAM2, DM, NTOK, DM, HH / 32,
            e_b2_l, 0, cnt, offs, perm, 2, top_w,
            (long long)DM * 2 * HH, (long long)DM, 0, 0);

        // x += LN2(MAM2); fused: emit XS for next layer's in_proj
        ln_residual_kernel<<<NTOK, 256, 0, stream>>>(
            X, MAM2, ln2_g + lay * DM, ln2_b + lay * DM, XS, nullptr);
    }

    // pooling + head
    rowmask_kernel<<<NTOK, 256, 0, stream>>>(X, maskf);
    cntb_kernel<<<BB, 256, 0, stream>>>(maskf, cntb);
    pooled_kernel<<<dim3(DM / 256, BB, 1), 256, 0, stream>>>(X, maskf, cntb, pooled);
    head_kernel<<<BB, 128, 0, stream>>>(pooled, fc1_w, fc1_b, fc2_w, fc2_b, outp);
}

// Round 4
// 1781.412 us; speedup vs baseline: 1.4076x; 1.0121x over previous
//
#include <hip/hip_runtime.h>
#include <hip/hip_bf16.h>

using bf = __hip_bfloat16;
typedef unsigned short u16;

// Model dims
#define V_   32000
#define DM   1024
#define LQ   1024
#define BB   4
#define NLAY 2
#define NE   8
#define HH   1024
#define DS   16
#define DC   4
#define DI   2048
#define DTR  64
#define NTOK (BB*LQ)   // 4096

// scan chunking
#define NC 16
#define CL (LQ/NC)     // 64

typedef __attribute__((ext_vector_type(8))) short s8v;
typedef __attribute__((ext_vector_type(4))) float f4v;

__device__ inline float tofl(float x) { return x; }
__device__ inline float tofl(bf x) { return __bfloat162float(x); }

template<typename T> __device__ inline T fromf(float v);
template<> __device__ inline float fromf<float>(float v) { return v; }
template<> __device__ inline bf fromf<bf>(float v) { return __float2bfloat16(v); }

__device__ inline u16 f2bfu(float x) {
    bf h = __float2bfloat16(x);
    return __builtin_bit_cast(u16, h);
}
__device__ inline float bfu2f(u16 u) {
    bf h = __builtin_bit_cast(bf, u);
    return __bfloat162float(h);
}

__device__ inline f4v mfma16(s8v a, s8v b, f4v c) {
    return __builtin_amdgcn_mfma_f32_16x16x32_bf16(a, b, c, 0, 0, 0);
}

// async global->LDS, 16B per lane. LDS dest is wave-uniform base + lane*16;
// global src is per-lane.
__device__ __forceinline__ void gl2lds16(const u16* g, u16* l) {
    __builtin_amdgcn_global_load_lds(
        (const __attribute__((address_space(1))) unsigned int*)g,
        (__attribute__((address_space(3))) unsigned int*)l, 16, 0, 0);
}

// ---------------------------------------------------------------------------
// split2: f32 [R,K] (row stride ldin) -> bf16 [R,2K]; per 32-col block b:
// out[r][b*64 + j]   = bf16(x)          (hi)
// out[r][b*64+32+ j] = bf16(x - hi)     (lo)
// ---------------------------------------------------------------------------
__global__ __launch_bounds__(256) void split2_kernel(
    const float* __restrict__ in, int ldin,
    u16* __restrict__ out, int K)
{
    int id = blockIdx.x * 256 + threadIdx.x;
    int e4 = id * 4;
    int r = e4 / K;
    int k = e4 - r * K;
    float4 v = *(const float4*)(in + (size_t)r * ldin + k);
    int b = k >> 5, j = k & 31;
    ushort4 hi, lo;
    hi.x = f2bfu(v.x); lo.x = f2bfu(v.x - bfu2f(hi.x));
    hi.y = f2bfu(v.y); lo.y = f2bfu(v.y - bfu2f(hi.y));
    hi.z = f2bfu(v.z); lo.z = f2bfu(v.z - bfu2f(hi.z));
    hi.w = f2bfu(v.w); lo.w = f2bfu(v.w - bfu2f(hi.w));
    u16* o = out + (size_t)r * (2 * K) + b * 64 + j;
    *(ushort4*)o = hi;
    *(ushort4*)(o + 32) = lo;
}

__global__ __launch_bounds__(256) void zerof4_kernel(float4* __restrict__ p) {
    p[(size_t)blockIdx.x * 256 + threadIdx.x] = make_float4(0.f, 0.f, 0.f, 0.f);
}

// ---------------------------------------------------------------------------
// Deep-pipelined 3-term split GEMM with fine phases (in_proj shape).
// 256x128 tile, 8 waves, BK=32 (64 u16 hi|lo), 3 LDS buffers, 2-ahead
// prefetch. Each K-step = 4 phases {ds_read / stage-issue -> s_barrier ->
// lgkmcnt(0) -> setprio MFMA setprio -> s_barrier}; ONE counted vmcnt per
// K-step placed at the END of the step BEFORE the inter-step s_barrier, so
// every wave's buffer-(q+1) DMAs have landed before any wave reads them
// (vmcnt is per-wave; the barrier makes the guarantee collective).
// XCD-swizzled blockIdx. Per-acc-element MFMA order: q ascending;
// hi*hi, hi*lo, lo*hi (numerics identical to gemm_s<...,3,...>).
// Requires M%256==0, N%128==0, nwg%8==0, K32>=2.
// ---------------------------------------------------------------------------
__global__ __launch_bounds__(512) void gemm_pipe3(
    const u16* __restrict__ A, int lda,
    const u16* __restrict__ Bw, int ldb,
    bf* __restrict__ C, int ldc,
    int K32)
{
    __shared__ u16 LA[3][256 * 64];   // 96 KB
    __shared__ u16 LB[3][128 * 64];   // 48 KB

    int t = threadIdx.x, lane = t & 63, wv = t >> 6;
    // bijective XCD swizzle (nwg % 8 == 0)
    int lin = blockIdx.y * gridDim.x + blockIdx.x;
    int cpx = (gridDim.x * gridDim.y) >> 3;
    int lin2 = (lin & 7) * cpx + (lin >> 3);
    int bx = lin2 % gridDim.x, by = lin2 / gridDim.x;
    int m0 = by * 256, n0 = bx * 128;
    int wm = (wv >> 1) * 64, wn = (wv & 1) * 64;
    int fr = lane & 15, kq = lane >> 4;

    // staging lane geometry: lane covers row (lane>>3) of an 8-row group,
    // LDS chunk (lane&7); fetches global chunk (lane&7)^(row&7) so a
    // swizzled read LDS[R][g^(R&7)] returns global chunk g.
    int lrow8 = lane >> 3;
    int lchunk = (lane & 7) ^ lrow8;
    const u16* Abase = A + (size_t)(m0 + wv * 32 + lrow8) * lda + lchunk * 8;
    const u16* Bbase = Bw + (size_t)(n0 + wv * 16 + lrow8) * ldb + lchunk * 8;

    f4v acc[4][4];
#pragma unroll
    for (int i = 0; i < 4; i++)
#pragma unroll
        for (int j = 0; j < 4; j++) acc[i][j] = 0.f;

    auto stageA2 = [&](int q, int s, int half) {
        const u16* ap = Abase + (size_t)q * 64;
#pragma unroll
        for (int j = half * 2; j < half * 2 + 2; j++)
            gl2lds16(ap + (size_t)(j * 8) * lda, &LA[s][(wv * 32 + j * 8) * 64]);
    };
    auto stageB2 = [&](int q, int s) {
        const u16* bp = Bbase + (size_t)q * 64;
#pragma unroll
        for (int j = 0; j < 2; j++)
            gl2lds16(bp + (size_t)(j * 8) * ldb, &LB[s][(wv * 16 + j * 8) * 64]);
    };

    // prologue: stage K-steps 0 and 1 (6 loads each), then make buffer 0
    // collectively visible: own-wave vmcnt(6) + barrier.
    stageA2(0, 0, 0); stageA2(0, 0, 1); stageB2(0, 0);
    stageA2(1, 1, 0); stageA2(1, 1, 1); stageB2(1, 1);
    asm volatile("s_waitcnt vmcnt(6)" ::: "memory");
    __builtin_amdgcn_sched_barrier(0);
    __builtin_amdgcn_s_barrier();

    for (int q = 0; q < K32; ++q) {
        int s = q % 3;
        int s2 = (q + 2) % 3;

        s8v ah[4], al[4];
#pragma unroll
        for (int p = 0; p < 4; p++) {
            // ---- ds reads for this phase (buffer s: landed + barrier'd) ----
            if (p == 0) {
#pragma unroll
                for (int mi = 0; mi < 4; mi++) {
                    int R = wm + mi * 16 + fr;
                    int c = kq ^ (R & 7);
                    ah[mi] = *(const s8v*)&LA[s][R * 64 + c * 8];
                    al[mi] = *(const s8v*)&LA[s][R * 64 + (c ^ 4) * 8];
                }
            }
            s8v bh, bl;
            {
                int R = wn + p * 16 + fr;
                int c = kq ^ (R & 7);
                bh = *(const s8v*)&LB[s][R * 64 + c * 8];
                bl = *(const s8v*)&LB[s][R * 64 + (c ^ 4) * 8];
            }
            // ---- stage-issue share for K-step q+2 (buffer s2 is dead:
            //      its step-(q-1) reads drained before the last barrier) ----
            if (q + 2 < K32) {
                if (p == 0) stageA2(q + 2, s2, 0);
                else if (p == 1) stageA2(q + 2, s2, 1);
                else if (p == 2) stageB2(q + 2, s2);
            }
            __builtin_amdgcn_s_barrier();
            asm volatile("s_waitcnt lgkmcnt(0)" ::: "memory");
            __builtin_amdgcn_sched_barrier(0);
            __builtin_amdgcn_s_setprio(1);
#pragma unroll
            for (int mi = 0; mi < 4; mi++) {
                acc[mi][p] = mfma16(ah[mi], bh, acc[mi][p]);   // hi*hi
                acc[mi][p] = mfma16(ah[mi], bl, acc[mi][p]);   // hi*lo
                acc[mi][p] = mfma16(al[mi], bh, acc[mi][p]);   // lo*hi
            }
            __builtin_amdgcn_s_setprio(0);
            __builtin_amdgcn_sched_barrier(0);
            if (p < 3) __builtin_amdgcn_s_barrier();
        }
        // ---- end of step: make buffer (q+1) collectively visible ----
        if (q + 1 < K32) {
            if (q + 2 < K32) asm volatile("s_waitcnt vmcnt(6)" ::: "memory");
            else             asm volatile("s_waitcnt vmcnt(0)" ::: "memory");
            __builtin_amdgcn_sched_barrier(0);
            __builtin_amdgcn_s_barrier();
        }
    }

    // epilogue: C row = (lane>>4)*4 + reg, col = lane&15
#pragma unroll
    for (int mi = 0; mi < 4; mi++) {
#pragma unroll
        for (int r4 = 0; r4 < 4; r4++) {
            int m = m0 + wm + mi * 16 + kq * 4 + r4;
#pragma unroll
            for (int ni = 0; ni < 4; ni++) {
                int n = n0 + wn + ni * 16 + fr;
                C[(size_t)m * ldc + n] = __float2bfloat16(acc[mi][ni][r4]);
            }
        }
    }
}

// ---------------------------------------------------------------------------
// MFMA GEMM on pre-split bf16 operands (2-barrier structure; small/odd shapes
// and expert gather/scatter). SPLITOUT=1: epilogue writes split2-format u16
// pairs. bmap non-null: blockIdx.y indexes a (expert, m-tile) block map.
// ---------------------------------------------------------------------------
template<typename TC, int TERMS, int BN, int SPLITOUT = 0>
__global__ __launch_bounds__(256, 3) void gemm_s(
    const u16* __restrict__ A, int lda,
    const u16* __restrict__ Bw, int ldb,
    TC* __restrict__ C, int ldc,
    int M, int N, int K32,
    const float* __restrict__ bias, int epi,        // 0 none, 1 softplus, 2 relu
    const int* __restrict__ cnt, const int* __restrict__ offs,
    const int* __restrict__ perm, int permmode,
    const float* __restrict__ scale,
    long long strideB_e, long long stride_bias_e,
    int nqz, int atomic_out,
    const int* __restrict__ bmap)
{
    int e = blockIdx.z, m0;
    if (bmap) {
        int by = blockIdx.y;
        if (by >= bmap[0]) return;
        e = bmap[1 + 2 * by];
        m0 = bmap[2 + 2 * by] * 128;
    } else {
        m0 = blockIdx.y * 128;
    }
    int Meff = M, rowoff = 0;
    int q0 = 0, q1 = K32;
    if (cnt) {
        Meff = cnt[e];
        rowoff = offs[e];
        Bw += (size_t)e * strideB_e;
        if (bias) bias += (size_t)e * stride_bias_e;
    } else if (nqz) {
        q0 = e * nqz; q1 = q0 + nqz;
    }
    if (m0 >= Meff) return;
    int n0 = blockIdx.x * BN;

    constexpr int MI  = (BN == 128) ? 4 : 2;
    constexpr int NBR = BN / 64;                 // B staging rounds

    __shared__ u16 AsH[128 * 32];
    __shared__ u16 AsL[(TERMS == 3) ? 128 * 32 : 8];
    __shared__ u16 BsH[BN * 32];
    __shared__ u16 BsL[BN * 32];

    int t = threadIdx.x, lane = t & 63, wv = t >> 6;
    int wm = (BN == 128) ? (wv & 1) * 64 : wv * 32;
    int wn = (BN == 128) ? (wv >> 1) * 64 : 0;
    int fr = lane & 15, kq = lane >> 4;
    int chunk = lane & 3;

    int arow[2], brow[2];
#pragma unroll
    for (int r = 0; r < 2; r++) {
        int m = m0 + r * 64 + wv * 16 + (lane >> 2);
        int ar = rowoff + ((m < Meff) ? m : 0);
        arow[r] = (permmode & 1) ? perm[ar] : ar;
    }
#pragma unroll
    for (int r = 0; r < NBR; r++) {
        int n = n0 + r * 64 + wv * 16 + (lane >> 2);
        brow[r] = (n < N) ? n : 0;
    }

    f4v acc[MI][4];
#pragma unroll
    for (int i = 0; i < MI; i++)
#pragma unroll
        for (int j = 0; j < 4; j++) acc[i][j] = 0.f;

    for (int q = q0; q < q1; ++q) {
        size_t acol = (TERMS == 3) ? ((size_t)q * 64 + chunk * 8)
                                   : ((size_t)q * 32 + chunk * 8);
        size_t bcol = (size_t)q * 64 + chunk * 8;
#pragma unroll
        for (int r = 0; r < 2; r++) {
            const u16* ap = A + (size_t)arow[r] * lda + acol;
            gl2lds16(ap, &AsH[(r * 64 + wv * 16) * 32]);
            if constexpr (TERMS == 3)
                gl2lds16(ap + 32, &AsL[(r * 64 + wv * 16) * 32]);
        }
#pragma unroll
        for (int r = 0; r < NBR; r++) {
            const u16* bp = Bw + (size_t)brow[r] * ldb + bcol;
            gl2lds16(bp, &BsH[(r * 64 + wv * 16) * 32]);
            gl2lds16(bp + 32, &BsL[(r * 64 + wv * 16) * 32]);
        }
        __syncthreads();

        s8v ahf[MI], bhf[4], blf[4];
#pragma unroll
        for (int mi = 0; mi < MI; mi++)
            ahf[mi] = *(const s8v*)&AsH[(wm + mi * 16 + fr) * 32 + kq * 8];
#pragma unroll
        for (int ni = 0; ni < 4; ni++)
            bhf[ni] = *(const s8v*)&BsH[(wn + ni * 16 + fr) * 32 + kq * 8];
#pragma unroll
        for (int ni = 0; ni < 4; ni++)
            blf[ni] = *(const s8v*)&BsL[(wn + ni * 16 + fr) * 32 + kq * 8];
#pragma unroll
        for (int mi = 0; mi < MI; mi++)
#pragma unroll
            for (int ni = 0; ni < 4; ni++) {
                acc[mi][ni] = mfma16(ahf[mi], bhf[ni], acc[mi][ni]);
                acc[mi][ni] = mfma16(ahf[mi], blf[ni], acc[mi][ni]);
            }
        if constexpr (TERMS == 3) {
            s8v alf[MI];
#pragma unroll
            for (int mi = 0; mi < MI; mi++)
                alf[mi] = *(const s8v*)&AsL[(wm + mi * 16 + fr) * 32 + kq * 8];
#pragma unroll
            for (int mi = 0; mi < MI; mi++)
#pragma unroll
                for (int ni = 0; ni < 4; ni++)
                    acc[mi][ni] = mfma16(alf[mi], bhf[ni], acc[mi][ni]);
        }
        __syncthreads();
    }

#pragma unroll
    for (int mi = 0; mi < MI; mi++) {
#pragma unroll
        for (int r4 = 0; r4 < 4; r4++) {
            int m = m0 + wm + mi * 16 + kq * 4 + r4;
            if (m >= Meff) continue;
            long long crow;
            float sc = 1.f;
            int ar = rowoff + m;
            if (permmode & 2) { int tok = perm[ar]; crow = tok; sc = scale[tok]; }
            else crow = ar;
#pragma unroll
            for (int ni = 0; ni < 4; ni++) {
                int n = n0 + wn + ni * 16 + fr;
                if (n >= N) continue;
                float v = acc[mi][ni][r4];
                if (bias) v += bias[n];
                if (epi == 1) v = (v > 20.f) ? v : log1pf(__expf(v));
                else if (epi == 2) v = fmaxf(v, 0.f);
                v *= sc;
                if constexpr (SPLITOUT) {
                    u16 hi = f2bfu(v);
                    u16 lo = f2bfu(v - bfu2f(hi));
                    size_t o = (size_t)crow * ldc + ((n >> 5) << 6) + (n & 31);
                    ((u16*)C)[o] = hi;
                    ((u16*)C)[o + 32] = lo;
                } else {
                    long long idx = crow * ldc + n;
                    if constexpr (sizeof(TC) == 4) {
                        if (atomic_out) atomicAdd((float*)C + idx, v);
                        else C[idx] = fromf<TC>(v);
                    } else {
                        C[idx] = fromf<TC>(v);
                    }
                }
            }
        }
    }
}

// ---------------------------------------------------------------------------
// embed + split2(X) fused
__global__ __launch_bounds__(256) void embed_kernel(
    const int* __restrict__ tokens, const float* __restrict__ emb,
    const float* __restrict__ pos, float* __restrict__ X,
    u16* __restrict__ xs)
{
    int id = blockIdx.x * 256 + threadIdx.x;   // NTOK*DM threads
    int r = id >> 10, d = id & 1023;
    int l = r & (LQ - 1);
    int tok = tokens[r];
    float val = emb[(size_t)tok * DM + d] + pos[l * DM + d];
    X[id] = val;
    u16 hi = f2bfu(val);
    u16 lo = f2bfu(val - bfu2f(hi));
    size_t o2 = (size_t)r * (2 * DM) + ((d >> 5) << 6) + (d & 31);
    xs[o2] = hi;
    xs[o2 + 32] = lo;
}

// causal depthwise conv (DC=4) + SiLU, 2 channels/thread.
__global__ __launch_bounds__(256) void conv_kernel(
    const bf* __restrict__ XZ, const float* __restrict__ cw,
    const float* __restrict__ cb, bf* __restrict__ UC)
{
    int id = blockIdx.x * 256 + threadIdx.x;   // NTOK*DI/2 threads
    int d = (id & (DI / 2 - 1)) * 2;
    int r = id >> 10;
    int l = r & (LQ - 1);
    float a0 = cb[d], a1 = cb[d + 1];
#pragma unroll
    for (int j = 0; j < DC; j++) {
        int ll = l - (DC - 1) + j;
        if (ll >= 0) {
            const u16* p = (const u16*)XZ + (size_t)(r - (DC - 1) + j) * (2 * DI) + d;
            ushort2 uv = *(const ushort2*)p;
            a0 += bfu2f(uv.x) * cw[d * DC + j];
            a1 += bfu2f(uv.y) * cw[(d + 1) * DC + j];
        }
    }
    float s0 = a0 / (1.f + __expf(-a0));
    float s1 = a1 / (1.f + __expf(-a1));
    ushort2 ov;
    ov.x = f2bfu(s0); ov.y = f2bfu(s1);
    *(ushort2*)((u16*)UC + (size_t)r * DI + d) = ov;
}

// ---------------------------------------------------------------------------
// Chunked parallel scan. PHASE 1 writes the gated output directly in split2
// format (DTS, overlaying DT's storage): per-t-step __syncthreads separates
// this step's reads (rows r,r+1) from the row-r split2 write (the block's
// d-range [256x,256x+256) maps onto exactly the same row-byte range
// [1024x,1024x+1024) for both the f32 reads and the split2 writes).
// PHASE 0 additionally zeroes cnt (block 0) for the downstream gate.
// ---------------------------------------------------------------------------
template<int PHASE>
__global__ __launch_bounds__(256) void scan_chunk(
    const bf* __restrict__ UC, float* __restrict__ DT,
    const float* __restrict__ W96, const bf* __restrict__ XZ,
    const float* __restrict__ A_log, const float* __restrict__ D_ssm,
    float* __restrict__ Hout, float* __restrict__ Stot,
    const float* __restrict__ Hin,
    u16* __restrict__ DTS, int* __restrict__ cntz)
{
    if (PHASE == 0 && blockIdx.x == 0 && blockIdx.y == 0 && blockIdx.z == 0
        && threadIdx.x < 8) cntz[threadIdx.x] = 0;
    int d = blockIdx.x * 256 + threadIdx.x;    // DI/256 blocks in x
    int c = blockIdx.y, b = blockIdx.z;
    float A[DS];
#pragma unroll
    for (int n = 0; n < DS; n++) A[n] = -__expf(A_log[d * DS + n]);
    float Dv = D_ssm[d];
    float h[DS];
    size_t hbase = ((size_t)(b * DI + d) * NC + c) * DS;
    if (PHASE == 0) {
#pragma unroll
        for (int n = 0; n < DS; n++) h[n] = 0.f;
    } else {
#pragma unroll
        for (int n = 0; n < DS; n += 4)
            *(float4*)&h[n] = *(const float4*)&Hin[hbase + n];
    }
    float S = 0.f;

    size_t rowb = (size_t)((b << 10) + c * CL);
    float u_c = tofl(UC[rowb * DI + d]);
    float dt_c = DT[rowb * DI + d];

    for (int t = 0; t < CL; t++) {
        size_t r = rowb + t;
        float u_n = 0.f, dt_n = 0.f;
        if (t + 1 < CL) {                       // prefetch next step
            u_n = tofl(UC[(r + 1) * DI + d]);
            dt_n = DT[(r + 1) * DI + d];
        }
        float du = dt_c * u_c;
        if (PHASE == 0) S += dt_c;
        float y = 0.f;
#pragma unroll
        for (int n = 0; n < DS; n++) {
            float Bv = W96[r * 96 + DTR + n];
            h[n] = __expf(dt_c * A[n]) * h[n] + du * Bv;
            if (PHASE == 1) y += h[n] * W96[r * 96 + DTR + DS + n];
        }
        if (PHASE == 1) {
            float z = tofl(XZ[r * (2 * DI) + DI + d]);
            float sil = z / (1.f + __expf(-z));
            float yv = (y + u_c * Dv) * sil;
            __syncthreads();   // all row r/r+1 reads done before row-r write
            u16 hi = f2bfu(yv);
            u16 lo = f2bfu(yv - bfu2f(hi));
            size_t o2 = r * (2 * DI) + ((d >> 5) << 6) + (d & 31);
            DTS[o2] = hi;
            DTS[o2 + 32] = lo;
        }
        u_c = u_n; dt_c = dt_n;
    }
    if (PHASE == 0) {
#pragma unroll
        for (int n = 0; n < DS; n += 4)
            *(float4*)&Hout[hbase + n] = *(const float4*)&h[n];
        Stot[(size_t)(b * DI + d) * NC + c] = S;
    }
}

__global__ __launch_bounds__(256) void scan_combine(
    const float* __restrict__ Hout, const float* __restrict__ Stot,
    const float* __restrict__ A_log, float* __restrict__ Hin)
{
    int id = blockIdx.x * 256 + threadIdx.x;   // BB*DI*DS = 131072 threads
    int n = id & (DS - 1);
    int d = (id >> 4) & (DI - 1);
    int b = id >> 15;
    float A = -__expf(A_log[d * DS + n]);
    float h = 0.f;
    size_t base = (size_t)(b * DI + d) * NC * DS + n;
    size_t sbase = (size_t)(b * DI + d) * NC;
    for (int c = 0; c < NC; c++) {
        Hin[base + (size_t)c * DS] = h;
        h = __expf(A * Stot[sbase + c]) * h + Hout[base + (size_t)c * DS];
    }
}

// ---------------------------------------------------------------------------
// LN(src)*g+b added into residual X. Emits split2(updated X) into xs.
__global__ __launch_bounds__(256) void ln_residual_kernel(
    float* __restrict__ X, const float* __restrict__ src,
    const float* __restrict__ g, const float* __restrict__ b,
    u16* __restrict__ xs)
{
    int row = blockIdx.x, tid = threadIdx.x;
    __shared__ float red[256];
    float v[4];
    float s = 0.f;
#pragma unroll
    for (int i = 0; i < 4; i++) { v[i] = src[(size_t)row * DM + tid + 256 * i]; s += v[i]; }
    red[tid] = s; __syncthreads();   // after this barrier all src reads are done
    for (int o = 128; o > 0; o >>= 1) { if (tid < o) red[tid] += red[tid + o]; __syncthreads(); }
    float mean = red[0] * (1.f / DM);
    __syncthreads();
    float vs = 0.f;
#pragma unroll
    for (int i = 0; i < 4; i++) { float dd = v[i] - mean; vs += dd * dd; }
    red[tid] = vs; __syncthreads();
    for (int o = 128; o > 0; o >>= 1) { if (tid < o) red[tid] += red[tid + o]; __syncthreads(); }
    float rstd = rsqrtf(red[0] * (1.f / DM) + 1e-5f);
#pragma unroll
    for (int i = 0; i < 4; i++) {
        int c = tid + 256 * i;
        float nx = X[(size_t)row * DM + c] + (v[i] - mean) * rstd * g[c] + b[c];
        X[(size_t)row * DM + c] = nx;
        u16 hi = f2bfu(nx);
        u16 lo = f2bfu(nx - bfu2f(hi));
        size_t o2 = (size_t)row * (2 * DM) + ((c >> 5) << 6) + (c & 31);
        xs[o2] = hi;
        xs[o2 + 32] = lo;
    }
}

// gate: logits -> softmax max/argmax -> top_idx/top_w + per-expert counts
// (exact summation order of the original passing kernel — do not fuse/reorder:
//  argmax near-ties make routing sensitive to reassociation)
__global__ __launch_bounds__(64) void gate_kernel(
    const float* __restrict__ X, const float* __restrict__ gw, const float* __restrict__ gb,
    int* __restrict__ top_idx, float* __restrict__ top_w, int* __restrict__ cnt)
{
    int n = blockIdx.x;
    int lane = threadIdx.x;
    float acc[NE] = {};
    for (int k = lane; k < DM; k += 64) {
        float xv = X[(size_t)n * DM + k];
#pragma unroll
        for (int e = 0; e < NE; e++) acc[e] += xv * gw[e * DM + k];
    }
#pragma unroll
    for (int e = 0; e < NE; e++)
        for (int o = 32; o > 0; o >>= 1) acc[e] += __shfl_down(acc[e], o);
    if (lane == 0) {
        float logits[NE];
        float best = -1e30f; int bi = 0;
#pragma unroll
        for (int e = 0; e < NE; e++) {
            logits[e] = acc[e] + gb[e];
            if (logits[e] > best) { best = logits[e]; bi = e; }
        }
        float s = 0.f;
#pragma unroll
        for (int e = 0; e < NE; e++) s += __expf(logits[e] - best);
        top_idx[n] = bi;
        top_w[n] = 1.f / s;
        atomicAdd(&cnt[bi], 1);
    }
}

// offsets + expert block map: bmap[0]=nblocks; bmap[1+2i]=expert, bmap[2+2i]=m-tile
__global__ void offsets_kernel(const int* __restrict__ cnt, int* __restrict__ offs,
                               int* __restrict__ pos, int* __restrict__ bmap)
{
    if (threadIdx.x == 0) {
        int a = 0;
        for (int e = 0; e < NE; e++) { offs[e] = a; a += cnt[e]; pos[e] = 0; }
        offs[NE] = a;
        int nb = 0;
        for (int e = 0; e < NE; e++)
            for (int yb = 0; yb * 128 < cnt[e]; yb++) {
                bmap[1 + 2 * nb] = e; bmap[2 + 2 * nb] = yb; nb++;
            }
        bmap[0] = nb;
    }
}

__global__ __launch_bounds__(256) void scatter_kernel(
    const int* __restrict__ top_idx, const int* __restrict__ offs,
    int* __restrict__ pos, int* __restrict__ perm)
{
    int n = blockIdx.x * 256 + threadIdx.x;
    if (n >= NTOK) return;
    int e = top_idx[n];
    int slot = atomicAdd(&pos[e], 1);
    perm[offs[e] + slot] = n;
}

__global__ __launch_bounds__(256) void rowmask_kernel(const float* __restrict__ X, float* __restrict__ maskf)
{
    int row = blockIdx.x, tid = threadIdx.x;
    __shared__ float red[256];
    float s = 0.f;
    for (int i = tid; i < DM; i += 256) s += X[(size_t)row * DM + i];
    red[tid] = s; __syncthreads();
    for (int o = 128; o > 0; o >>= 1) { if (tid < o) red[tid] += red[tid + o]; __syncthreads(); }
    if (tid == 0) maskf[row] = (red[0] != 0.f) ? 1.f : 0.f;
}

// per-batch token count + zero pooled (pooled accumulated by atomics next)
__global__ __launch_bounds__(256) void cntb_kernel(const float* __restrict__ maskf,
                                                   float* __restrict__ cntb,
                                                   float* __restrict__ pooled)
{
    int b = blockIdx.x, tid = threadIdx.x;
    __shared__ float red[256];
    float s = 0.f;
    for (int i = tid; i < LQ; i += 256) s += maskf[b * LQ + i];
    red[tid] = s; __syncthreads();
    for (int o = 128; o > 0; o >>= 1) { if (tid < o) red[tid] += red[tid + o]; __syncthreads(); }
    if (tid == 0) cntb[b] = red[0];
    for (int i = tid; i < DM; i += 256) pooled[b * DM + i] = 0.f;
}

__global__ __launch_bounds__(256) void pooled_kernel(
    const float* __restrict__ X, const float* __restrict__ maskf,
    const float* __restrict__ cntb, float* __restrict__ pooled)
{
    int d = blockIdx.x * 256 + threadIdx.x;
    int b = blockIdx.y;
    int l0 = blockIdx.z * (LQ / 8);
    float s = 0.f;
    for (int l = l0; l < l0 + LQ / 8; l++)
        s += X[(size_t)((b << 10) + l) * DM + d] * maskf[(b << 10) + l];
    atomicAdd(&pooled[b * DM + d], s / fmaxf(cntb[b], 1.f));
}

__global__ __launch_bounds__(128) void head_kernel(
    const float* __restrict__ pooled,
    const float* __restrict__ fc1w, const float* __restrict__ fc1b,
    const float* __restrict__ fc2w, const float* __restrict__ fc2b,
    float* __restrict__ out)
{
    int b = blockIdx.x;
    int j = threadIdx.x;   // 128
    __shared__ float hbuf[128];
    float acc = fc1b[j];
    for (int k = 0; k < DM; k++) acc += pooled[b * DM + k] * fc1w[j * DM + k];
    hbuf[j] = fmaxf(acc, 0.f);
    __syncthreads();
    if (j < 2) {
        float o = fc2b[j];
        for (int k = 0; k < 128; k++) o += hbuf[k] * fc2w[j * 128 + k];
        out[b * 2 + j] = o;
    }
}

// ---------------------------------------------------------------------------
extern "C" void kernel_launch(void* const* d_in, const int* in_sizes, int n_in,
                              void* d_out, int out_size, void* d_ws, size_t ws_size,
                              hipStream_t stream)
{
    const int*   tokens = (const int*)d_in[0];
    const float* emb    = (const float*)d_in[1];
    const float* pos    = (const float*)d_in[2];
    const float* in_w   = (const float*)d_in[3];
    const float* conv_w = (const float*)d_in[4];
    const float* conv_b = (const float*)d_in[5];
    const float* xp_w   = (const float*)d_in[6];
    const float* dt_w   = (const float*)d_in[7];
    const float* dt_b   = (const float*)d_in[8];
    const float* A_log  = (const float*)d_in[9];
    const float* D_ssm  = (const float*)d_in[10];
    const float* out_w  = (const float*)d_in[11];
    const float* ln1_g  = (const float*)d_in[12];
    const float* ln1_b  = (const float*)d_in[13];
    const float* ln2_g  = (const float*)d_in[14];
    const float* ln2_b  = (const float*)d_in[15];
    const float* gate_w = (const float*)d_in[16];
    const float* gate_b = (const float*)d_in[17];
    const float* e_w1   = (const float*)d_in[18];
    const float* e_b1   = (const float*)d_in[19];
    const float* e_w2   = (const float*)d_in[20];
    const float* e_b2   = (const float*)d_in[21];
    const float* fc1_w  = (const float*)d_in[22];
    const float* fc1_b  = (const float*)d_in[23];
    const float* fc2_w  = (const float*)d_in[24];
    const float* fc2_b  = (const float*)d_in[25];
    float* outp = (float*)d_out;

    // workspace overlays:
    //  xzraw (33.5MB): XZ -> out_w split (WBX) -> MAM2(front)+H1S(back)
    //  ucraw (16.8MB): XS -> UC -> MAM1/XS(ln1) -> XS(ln2)
    //  dtraw (33.5MB): WB(in_w/xp_w splits) -> DT -> DTS(scan1, in place)
    //                  -> WB(e_w1/e_w2 splits)
    //  Hout/Hin (8MB): scan state; also W96S / dt_w-split scratch
    char* wsb = (char*)d_ws;
    size_t off = 0;
    auto alloc = [&](size_t bytes) { char* p = wsb + off; off += (bytes + 255) & ~(size_t)255; return p; };
    float* X    = (float*)alloc((size_t)NTOK * DM * 4);
    char* xzraw = (char*)alloc((size_t)NTOK * 2 * DI * 2);
    char* ucraw = (char*)alloc((size_t)NTOK * DI * 2);
    float* W96  = (float*)alloc((size_t)NTOK * 96 * 4);
    char* dtraw = (char*)alloc((size_t)NTOK * DI * 4);
    float* Hout = (float*)alloc((size_t)BB * DI * NC * DS * 4);
    float* Hin  = (float*)alloc((size_t)BB * DI * NC * DS * 4);
    float* Stot = (float*)alloc((size_t)BB * DI * NC * 4);
    float* top_w  = (float*)alloc(NTOK * 4);
    float* maskf  = (float*)alloc(NTOK * 4);
    float* pooled = (float*)alloc(BB * DM * 4);
    float* cntb   = (float*)alloc(64);
    int* top_idx  = (int*)alloc(NTOK * 4);
    int* perm     = (int*)alloc(NTOK * 4);
    int* cnt      = (int*)alloc(64);
    int* offs     = (int*)alloc(64);
    int* posc     = (int*)alloc(64);
    int* bmap     = (int*)alloc(512);

    bf*    XZ   = (bf*)xzraw;
    bf*    UC   = (bf*)ucraw;
    float* DT   = (float*)dtraw;
    u16*   XS   = (u16*)ucraw;                                // X split2 [NTOK,2*DM]
    u16*   DTS  = (u16*)dtraw;                                // scan1 split2 out (in place)
    u16*   WBX  = (u16*)xzraw;                                // out_w split (over dead XZ)
    u16*   H1S  = (u16*)(xzraw + (size_t)NTOK * HH * 4);      // H1 split2 [NTOK,2*HH]
    float* MAM1 = (float*)ucraw;                              // mamba out f32 [NTOK,DM]
    float* MAM2 = (float*)xzraw;                              // moe out f32 [NTOK,DM]
    u16*   WB   = (u16*)dtraw;                                // weight split buffer
    u16*   WDT  = (u16*)Hin;                                  // dt_w split (0.5MB <= 8MB)
    u16*   W96S = (u16*)Hout;                                 // W96 split (1MB <= 8MB)

    embed_kernel<<<(NTOK * DM) / 256, 256, 0, stream>>>(tokens, emb, pos, X, XS);

    for (int lay = 0; lay < NLAY; lay++) {
        const float* in_w_l   = in_w   + (size_t)lay * 2 * DI * DM;
        const float* conv_w_l = conv_w + (size_t)lay * DI * DC;
        const float* conv_b_l = conv_b + (size_t)lay * DI;
        const float* xp_w_l   = xp_w   + (size_t)lay * 96 * DI;
        const float* dt_w_l   = dt_w   + (size_t)lay * DI * DTR;
        const float* dt_b_l   = dt_b   + (size_t)lay * DI;
        const float* A_log_l  = A_log  + (size_t)lay * DI * DS;
        const float* D_ssm_l  = D_ssm  + (size_t)lay * DI;
        const float* out_w_l  = out_w  + (size_t)lay * DM * DI;
        const float* gate_w_l = gate_w + (size_t)lay * NE * DM;
        const float* gate_b_l = gate_b + (size_t)lay * NE;
        const float* e_w1_l   = e_w1   + (size_t)lay * NE * HH * DM;
        const float* e_b1_l   = e_b1   + (size_t)lay * NE * HH;
        const float* e_w2_l   = e_w2   + (size_t)lay * NE * DM * HH;
        const float* e_b2_l   = e_b2   + (size_t)lay * NE * DM;

        // in_proj: XZ[4096,4096] = X @ in_w^T  (3-term split, 4-phase pipeline)
        split2_kernel<<<(2 * DI * DM) / 1024, 256, 0, stream>>>(in_w_l, DM, WB, DM);
        gemm_pipe3<<<dim3(2 * DI / 128, NTOK / 256, 1), 512, 0, stream>>>(
            XS, 2 * DM, WB, 2 * DM, XZ, 2 * DI, DM / 32);

        // depthwise conv + silu -> UC (overwrites XS; in_proj already consumed it)
        conv_kernel<<<(NTOK * DI / 2) / 256, 256, 0, stream>>>(XZ, conv_w_l, conv_b_l, UC);

        // x_proj: W96[4096,96] = UC @ xp_w^T  (A plain bf16; split-K x8, atomic)
        zerof4_kernel<<<(NTOK * 96) / 1024, 256, 0, stream>>>((float4*)W96);
        split2_kernel<<<(96 * DI) / 1024, 256, 0, stream>>>(xp_w_l, DI, WB, DI);
        gemm_s<float, 2, 128><<<dim3(1, 32, 8), 256, 0, stream>>>(
            (const u16*)UC, DI, WB, 2 * DI, W96, 96, NTOK, 96, DI / 32,
            nullptr, 0, nullptr, nullptr, nullptr, 0, nullptr, 0, 0, (DI / 32) / 8, 1, nullptr);

        // dt_proj + softplus: DT = softplus(W96[:, :64] @ dt_w^T + dt_b)
        split2_kernel<<<(DI * DTR) / 1024, 256, 0, stream>>>(dt_w_l, DTR, WDT, DTR);
        split2_kernel<<<(NTOK * DTR) / 1024, 256, 0, stream>>>(W96, 96, W96S, DTR);
        gemm_s<float, 3, 128><<<dim3(16, 32, 1), 256, 0, stream>>>(
            W96S, 2 * DTR, WDT, 2 * DTR, DT, DI, NTOK, DI, DTR / 32,
            dt_b_l, 1, nullptr, nullptr, nullptr, 0, nullptr, 0, 0, 0, 0, nullptr);

        // chunked scan: phase0 (zeros cnt) -> combine -> phase1 (emits DTS)
        scan_chunk<0><<<dim3(DI / 256, NC, BB), 256, 0, stream>>>(
            UC, DT, W96, XZ, A_log_l, D_ssm_l, Hout, Stot, nullptr, nullptr, cnt);
        scan_combine<<<(BB * DI * DS) / 256, 256, 0, stream>>>(Hout, Stot, A_log_l, Hin);
        scan_chunk<1><<<dim3(DI / 256, NC, BB), 256, 0, stream>>>(
            UC, DT, W96, XZ, A_log_l, D_ssm_l, Hout, Stot, Hin, DTS, nullptr);

        // out_proj: MAM1[4096,1024] = y @ out_w^T (A=DTS in place; B over dead XZ)
        split2_kernel<<<(DM * DI) / 1024, 256, 0, stream>>>(out_w_l, DI, WBX, DI);
        gemm_s<float, 3, 128><<<dim3(8, 32, 1), 256, 0, stream>>>(
            DTS, 2 * DI, WBX, 2 * DI, MAM1, DM, NTOK, DM, DI / 32,
            nullptr, 0, nullptr, nullptr, nullptr, 0, nullptr, 0, 0, 0, 0, nullptr);

        // x += LN1(MAM1); fused: emit XS = split2(updated X)
        ln_residual_kernel<<<NTOK, 256, 0, stream>>>(
            X, MAM1, ln1_g + lay * DM, ln1_b + lay * DM, XS);

        // MoE routing (cnt was zeroed by scan_chunk<0>)
        gate_kernel<<<NTOK, 64, 0, stream>>>(X, gate_w_l, gate_b_l, top_idx, top_w, cnt);
        offsets_kernel<<<1, 1, 0, stream>>>(cnt, offs, posc, bmap);
        scatter_kernel<<<NTOK / 256, 256, 0, stream>>>(top_idx, offs, posc, perm);

        // expert GEMM1: H1S (split2 u16) = relu(X[perm] @ w1[e]^T + b1[e])
        split2_kernel<<<((size_t)NE * HH * DM) / 1024, 256, 0, stream>>>(e_w1_l, DM, WB, DM);
        gemm_s<u16, 3, 128, 1><<<dim3(8, 40, 1), 256, 0, stream>>>(
            XS, 2 * DM, WB, 2 * DM, H1S, 2 * HH, NTOK, HH, DM / 32,
            e_b1_l, 2, cnt, offs, perm, 1, nullptr,
            (long long)HH * 2 * DM, (long long)HH, 0, 0, bmap);

        // expert GEMM2: MAM2[token] = top_w * (H1 @ w2[e]^T + b2[e])
        split2_kernel<<<((size_t)NE * DM * HH) / 1024, 256, 0, stream>>>(e_w2_l, HH, WB, HH);
        gemm_s<float, 3, 128><<<dim3(8, 40, 1), 256, 0, stream>>>(
            H1S, 2 * HH, WB, 2 * HH, MAM2, DM, NTOK, DM, HH / 32,
            e_b2_l, 0, cnt, offs, perm, 2, top_w,
            (long long)DM * 2 * HH, (long long)DM, 0, 0, bmap);

        // x += LN2(MAM2); emit XS for next layer's in_proj
        ln_residual_kernel<<<NTOK, 256, 0, stream>>>(
            X, MAM2, ln2_g + lay * DM, ln2_b + lay * DM, XS);
    }

    // pooling + head
    rowmask_kernel<<<NTOK, 256, 0, stream>>>(X, maskf);
    cntb_kernel<<<BB, 256, 0, stream>>>(maskf, cntb, pooled);
    pooled_kernel<<<dim3(DM / 256, BB, 8), 256, 0, stream>>>(X, maskf, cntb, pooled);
    head_kernel<<<BB, 128, 0, stream>>>(pooled, fc1_w, fc1_b, fc2_w, fc2_b, outp);
}